// Round 1
// baseline (2405.867 us; speedup 1.0000x reference)
//
#include <hip/hip_runtime.h>
#include <cmath>

// ---------------- helpers ----------------

__device__ __forceinline__ unsigned f2s(float x) {
    unsigned u = __float_as_uint(x);
    return (u & 0x80000000u) ? ~u : (u | 0x80000000u);
}
__device__ __forceinline__ float s2f(unsigned s) {
    return (s & 0x80000000u) ? __uint_as_float(s & 0x7FFFFFFFu)
                             : __uint_as_float(~s);
}

// ---------------- GEMM: C[N,M] = A[N,K] @ B[K,M] (row-major, fp32) ----------------
// BM x BN tile per block, (BM/TM)x(BN/TN) threads, each computes TM x TN outputs.
// Requires: K % BK == 0, M % BN == 0. Rows bounds-checked against N.
template <int BM, int BN, int BK, int TM, int TN>
__global__ void gemm_kernel(const float* __restrict__ A, const float* __restrict__ B,
                            float* __restrict__ C, int N, int K, int M) {
    constexpr int TX = BN / TN;
    constexpr int TY = BM / TM;
    constexpr int NT = TX * TY;
    __shared__ float As[BK][BM + 1];
    __shared__ float Bs[BK][BN + 1];

    const int tid = threadIdx.x;
    const int tx = tid % TX, ty = tid / TX;
    const int rowBase = blockIdx.y * BM;
    const int colBase = blockIdx.x * BN;

    float acc[TM][TN];
#pragma unroll
    for (int i = 0; i < TM; i++)
#pragma unroll
        for (int j = 0; j < TN; j++) acc[i][j] = 0.f;

    for (int k0 = 0; k0 < K; k0 += BK) {
        for (int idx = tid; idx < BM * BK; idx += NT) {
            int r = idx / BK, c = idx % BK;
            int gr = rowBase + r;
            As[c][r] = (gr < N) ? A[(long)gr * K + k0 + c] : 0.f;
        }
        for (int idx = tid; idx < BK * BN; idx += NT) {
            int r = idx / BN, c = idx % BN;
            Bs[r][c] = B[(long)(k0 + r) * M + colBase + c];
        }
        __syncthreads();
#pragma unroll
        for (int k = 0; k < BK; k++) {
            float a[TM], b[TN];
#pragma unroll
            for (int i = 0; i < TM; i++) a[i] = As[k][ty * TM + i];
#pragma unroll
            for (int j = 0; j < TN; j++) b[j] = Bs[k][tx * TN + j];
#pragma unroll
            for (int i = 0; i < TM; i++)
#pragma unroll
                for (int j = 0; j < TN; j++) acc[i][j] += a[i] * b[j];
        }
        __syncthreads();
    }
#pragma unroll
    for (int i = 0; i < TM; i++) {
        int gr = rowBase + ty * TM + i;
        if (gr < N) {
#pragma unroll
            for (int j = 0; j < TN; j++) {
                C[(long)gr * M + colBase + tx * TN + j] = acc[i][j];
            }
        }
    }
}

// ---------------- el/er: per (node, head) dot(feat, attn) ----------------
// One wave (64 lanes) per (n,h); lane d contributes feat[n,h,d]*a[h,d].
template <int H, int D>
__global__ void el_er_kernel(const float* __restrict__ feat,
                             const float* __restrict__ al, const float* __restrict__ ar,
                             float* __restrict__ el, float* __restrict__ er, int N) {
    const int wid = (blockIdx.x * blockDim.x + threadIdx.x) >> 6;
    const int lane = threadIdx.x & 63;
    if (wid >= N * H) return;
    const int n = wid / H, h = wid % H;
    float vl = 0.f, vr = 0.f;
    if (lane < D) {
        float f = feat[((long)n * H + h) * D + lane];
        vl = f * al[h * D + lane];
        vr = f * ar[h * D + lane];
    }
#pragma unroll
    for (int off = 32; off > 0; off >>= 1) {
        vl += __shfl_down(vl, off);
        vr += __shfl_down(vr, off);
    }
    if (lane == 0) { el[wid] = vl; er[wid] = vr; }
}

// ---------------- edge pass 1: e = leaky_relu(el[src]+er[dst]); segment max ----------------
template <int H>
__global__ void edge_max_kernel(const int* __restrict__ src, const int* __restrict__ dst,
                                const float* __restrict__ el, const float* __restrict__ er,
                                float* __restrict__ e_buf, unsigned* __restrict__ emax, int E) {
    const int tid = blockIdx.x * blockDim.x + threadIdx.x;
    if (tid >= E * H) return;
    const int eidx = tid / H, h = tid % H;
    const int s = src[eidx], d = dst[eidx];
    float e = el[s * H + h] + er[d * H + h];
    e = (e >= 0.f) ? e : 0.2f * e;
    e_buf[tid] = e;
    atomicMax(&emax[d * H + h], f2s(e));
}

// ---------------- edge pass 2: ee = exp(e - max); segment sum ----------------
template <int H>
__global__ void edge_expsum_kernel(const int* __restrict__ dst, float* __restrict__ e_buf,
                                   const unsigned* __restrict__ emax,
                                   float* __restrict__ denom, int E) {
    const int tid = blockIdx.x * blockDim.x + threadIdx.x;
    if (tid >= E * H) return;
    const int eidx = tid / H, h = tid % H;
    const int d = dst[eidx];
    float ee = expf(e_buf[tid] - s2f(emax[d * H + h]));
    e_buf[tid] = ee;
    atomicAdd(&denom[d * H + h], ee);
}

// ---------------- edge pass 3: rst[dst] += feat[src] * (ee/denom[dst]) ----------------
template <int H, int D>
__global__ void aggregate_kernel(const int* __restrict__ src, const int* __restrict__ dst,
                                 const float* __restrict__ feat, const float* __restrict__ e_buf,
                                 const float* __restrict__ denom, float* __restrict__ rst, int E) {
    constexpr int HD = H * D;
    const long tid = (long)blockIdx.x * blockDim.x + threadIdx.x;
    if (tid >= (long)E * HD) return;
    const int eidx = (int)(tid / HD);
    const int c = (int)(tid % HD);
    const int h = c / D;
    const int s = src[eidx], d = dst[eidx];
    const float a = e_buf[(long)eidx * H + h] / denom[d * H + h];
    atomicAdd(&rst[(long)d * HD + c], feat[(long)s * HD + c] * a);
}

// ---------------- finalize: out = mish(rst + res + bias) ----------------
__global__ void finalize_mish_kernel(const float* __restrict__ rst, const float* __restrict__ res,
                                     const float* __restrict__ bias, float* __restrict__ out,
                                     long total, int C) {
    const long tid = (long)blockIdx.x * blockDim.x + threadIdx.x;
    if (tid >= total) return;
    float v = rst[tid] + res[tid] + bias[tid % C];
    float sp = (v > 20.f) ? v : log1pf(expf(v));
    out[tid] = v * tanhf(sp);
}

__global__ void finalize_out_kernel(const float* __restrict__ rst, const float* __restrict__ res,
                                    const float* __restrict__ bias, float* __restrict__ out,
                                    long total, int C) {
    const long tid = (long)blockIdx.x * blockDim.x + threadIdx.x;
    if (tid >= total) return;
    out[tid] = rst[tid] + res[tid] + bias[tid % C];
}

// ---------------- host orchestration ----------------

static inline int cdiv(long a, long b) { return (int)((a + b - 1) / b); }

extern "C" void kernel_launch(void* const* d_in, const int* in_sizes, int n_in,
                              void* d_out, int out_size, void* d_ws, size_t ws_size,
                              hipStream_t stream) {
    const float* x   = (const float*)d_in[0];
    const int*   src = (const int*)d_in[1];
    const int*   dst = (const int*)d_in[2];
    const float* W0  = (const float*)d_in[3];
    const float* al0 = (const float*)d_in[4];
    const float* ar0 = (const float*)d_in[5];
    const float* b0  = (const float*)d_in[6];
    const float* W1  = (const float*)d_in[7];
    const float* al1 = (const float*)d_in[8];
    const float* ar1 = (const float*)d_in[9];
    const float* b1  = (const float*)d_in[10];
    const float* W2  = (const float*)d_in[11];
    const float* al2 = (const float*)d_in[12];
    const float* ar2 = (const float*)d_in[13];
    const float* b2  = (const float*)d_in[14];
    const float* rW2 = (const float*)d_in[15];
    float* out = (float*)d_out;

    const int N = in_sizes[0] / 256;   // 50000
    const int E = in_sizes[1];         // 800000
    const int K = 256;

    // workspace layout (floats)
    float* F     = (float*)d_ws;          // N*256 feat
    float* R     = F + (long)N * 256;     // N*256 rst accumulator
    float* Hb    = R + (long)N * 256;     // N*256 hidden
    float* e_buf = Hb + (long)N * 256;    // E*4
    float* el    = e_buf + (long)E * 4;   // N*4
    float* er    = el + (long)N * 4;      // N*4
    unsigned* emax = (unsigned*)(er + (long)N * 4);  // N*4
    float* denom = (float*)(emax + (long)N * 4);     // N*4
    float* res2  = denom + (long)N * 4;   // N*16

    const int THREADS = 256;
    dim3 gemm_grid(256 / 64, cdiv(N, 64));
    dim3 gemm16_grid(1, cdiv(N, 64));

    // ================= Layer 0 (H=4, D=64), input x, residual = x =================
    {
        const int H = 4, D = 64;
        gemm_kernel<64, 64, 16, 4, 4><<<gemm_grid, 256, 0, stream>>>(x, W0, F, N, K, 256);
        hipMemsetAsync(R, 0, (long)N * 256 * 4, stream);
        hipMemsetAsync(emax, 0, (long)N * H * 4, stream);
        hipMemsetAsync(denom, 0, (long)N * H * 4, stream);
        el_er_kernel<4, 64><<<cdiv((long)N * H * 64, THREADS), THREADS, 0, stream>>>(F, al0, ar0, el, er, N);
        edge_max_kernel<4><<<cdiv((long)E * H, THREADS), THREADS, 0, stream>>>(src, dst, el, er, e_buf, emax, E);
        edge_expsum_kernel<4><<<cdiv((long)E * H, THREADS), THREADS, 0, stream>>>(dst, e_buf, emax, denom, E);
        aggregate_kernel<4, 64><<<cdiv((long)E * 256, THREADS), THREADS, 0, stream>>>(src, dst, F, e_buf, denom, R, E);
        finalize_mish_kernel<<<cdiv((long)N * 256, THREADS), THREADS, 0, stream>>>(R, x, b0, Hb, (long)N * 256, 256);
    }

    // ================= Layer 1 (H=4, D=64), input Hb, residual = Hb (in-place) ====
    {
        const int H = 4, D = 64;
        gemm_kernel<64, 64, 16, 4, 4><<<gemm_grid, 256, 0, stream>>>(Hb, W1, F, N, K, 256);
        hipMemsetAsync(R, 0, (long)N * 256 * 4, stream);
        hipMemsetAsync(emax, 0, (long)N * H * 4, stream);
        hipMemsetAsync(denom, 0, (long)N * H * 4, stream);
        el_er_kernel<4, 64><<<cdiv((long)N * H * 64, THREADS), THREADS, 0, stream>>>(F, al1, ar1, el, er, N);
        edge_max_kernel<4><<<cdiv((long)E * H, THREADS), THREADS, 0, stream>>>(src, dst, el, er, e_buf, emax, E);
        edge_expsum_kernel<4><<<cdiv((long)E * H, THREADS), THREADS, 0, stream>>>(dst, e_buf, emax, denom, E);
        aggregate_kernel<4, 64><<<cdiv((long)E * 256, THREADS), THREADS, 0, stream>>>(src, dst, F, e_buf, denom, R, E);
        finalize_mish_kernel<<<cdiv((long)N * 256, THREADS), THREADS, 0, stream>>>(R, Hb, b1, Hb, (long)N * 256, 256);
    }

    // ================= Layer 2 (H=1, D=16), input Hb, residual = Hb @ rW2 =========
    {
        const int H = 1, D = 16;
        gemm_kernel<64, 16, 16, 4, 4><<<gemm16_grid, 64, 0, stream>>>(Hb, W2, F, N, K, 16);
        gemm_kernel<64, 16, 16, 4, 4><<<gemm16_grid, 64, 0, stream>>>(Hb, rW2, res2, N, K, 16);
        hipMemsetAsync(R, 0, (long)N * 16 * 4, stream);
        hipMemsetAsync(emax, 0, (long)N * H * 4, stream);
        hipMemsetAsync(denom, 0, (long)N * H * 4, stream);
        el_er_kernel<1, 16><<<cdiv((long)N * H * 64, THREADS), THREADS, 0, stream>>>(F, al2, ar2, el, er, N);
        edge_max_kernel<1><<<cdiv((long)E * H, THREADS), THREADS, 0, stream>>>(src, dst, el, er, e_buf, emax, E);
        edge_expsum_kernel<1><<<cdiv((long)E * H, THREADS), THREADS, 0, stream>>>(dst, e_buf, emax, denom, E);
        aggregate_kernel<1, 16><<<cdiv((long)E * 16, THREADS), THREADS, 0, stream>>>(src, dst, F, e_buf, denom, R, E);
        finalize_out_kernel<<<cdiv((long)N * 16, THREADS), THREADS, 0, stream>>>(R, res2, b2, out, (long)N * 16, 16);
    }
}

// Round 2
// 1492.136 us; speedup vs baseline: 1.6124x; 1.6124x over previous
//
#include <hip/hip_runtime.h>
#include <cmath>

// ---------------- GEMM: C[N,M] = A[N,K] @ B[K,M] (row-major, fp32) ----------------
template <int BM, int BN, int BK, int TM, int TN>
__global__ void gemm_kernel(const float* __restrict__ A, const float* __restrict__ B,
                            float* __restrict__ C, int N, int K, int M) {
    constexpr int TX = BN / TN;
    constexpr int TY = BM / TM;
    constexpr int NT = TX * TY;
    __shared__ float As[BK][BM + 1];
    __shared__ float Bs[BK][BN + 1];

    const int tid = threadIdx.x;
    const int tx = tid % TX, ty = tid / TX;
    const int rowBase = blockIdx.y * BM;
    const int colBase = blockIdx.x * BN;

    float acc[TM][TN];
#pragma unroll
    for (int i = 0; i < TM; i++)
#pragma unroll
        for (int j = 0; j < TN; j++) acc[i][j] = 0.f;

    for (int k0 = 0; k0 < K; k0 += BK) {
        for (int idx = tid; idx < BM * BK; idx += NT) {
            int r = idx / BK, c = idx % BK;
            int gr = rowBase + r;
            As[c][r] = (gr < N) ? A[(long)gr * K + k0 + c] : 0.f;
        }
        for (int idx = tid; idx < BK * BN; idx += NT) {
            int r = idx / BN, c = idx % BN;
            Bs[r][c] = B[(long)(k0 + r) * M + colBase + c];
        }
        __syncthreads();
#pragma unroll
        for (int k = 0; k < BK; k++) {
            float a[TM], b[TN];
#pragma unroll
            for (int i = 0; i < TM; i++) a[i] = As[k][ty * TM + i];
#pragma unroll
            for (int j = 0; j < TN; j++) b[j] = Bs[k][tx * TN + j];
#pragma unroll
            for (int i = 0; i < TM; i++)
#pragma unroll
                for (int j = 0; j < TN; j++) acc[i][j] += a[i] * b[j];
        }
        __syncthreads();
    }
#pragma unroll
    for (int i = 0; i < TM; i++) {
        int gr = rowBase + ty * TM + i;
        if (gr < N) {
#pragma unroll
            for (int j = 0; j < TN; j++) {
                C[(long)gr * M + colBase + tx * TN + j] = acc[i][j];
            }
        }
    }
}

// ---------------- el/er: per (node, head) dot(feat, attn) ----------------
template <int H, int D>
__global__ void el_er_kernel(const float* __restrict__ feat,
                             const float* __restrict__ al, const float* __restrict__ ar,
                             float* __restrict__ el, float* __restrict__ er, int N) {
    const int wid = (blockIdx.x * blockDim.x + threadIdx.x) >> 6;
    const int lane = threadIdx.x & 63;
    if (wid >= N * H) return;
    const int n = wid / H, h = wid % H;
    float vl = 0.f, vr = 0.f;
    if (lane < D) {
        float f = feat[((long)n * H + h) * D + lane];
        vl = f * al[h * D + lane];
        vr = f * ar[h * D + lane];
    }
#pragma unroll
    for (int off = 32; off > 0; off >>= 1) {
        vl += __shfl_down(vl, off);
        vr += __shfl_down(vr, off);
    }
    if (lane == 0) { el[wid] = vl; er[wid] = vr; }
}

// ---------------- CSR build ----------------

__global__ void count_deg_kernel(const int* __restrict__ dst, int* __restrict__ deg, int E) {
    const int e = blockIdx.x * blockDim.x + threadIdx.x;
    if (e >= E) return;
    atomicAdd(&deg[dst[e]], 1);
}

// single-block exclusive scan over N entries -> row_ptr[0..N]
__global__ void exscan_kernel(const int* __restrict__ deg, int* __restrict__ row_ptr, int N) {
    __shared__ int smem[1024];
    __shared__ int s_carry;
    const int tid = threadIdx.x;
    if (tid == 0) s_carry = 0;
    __syncthreads();
    for (int base = 0; base < N; base += 1024) {
        const int carry = s_carry;
        const int i = base + tid;
        const int v = (i < N) ? deg[i] : 0;
        smem[tid] = v;
        __syncthreads();
        int acc = v;
        for (int off = 1; off < 1024; off <<= 1) {
            const int t = (tid >= off) ? smem[tid - off] : 0;
            __syncthreads();
            acc += t;
            smem[tid] = acc;
            __syncthreads();
        }
        if (i < N) row_ptr[i] = carry + acc - v;
        if (tid == 1023) s_carry = carry + acc;
        __syncthreads();
    }
    if (tid == 0) row_ptr[N] = s_carry;
}

__global__ void copy_int_kernel(const int* __restrict__ a, int* __restrict__ b, int n) {
    const int i = blockIdx.x * blockDim.x + threadIdx.x;
    if (i < n) b[i] = a[i];
}

__global__ void scatter_kernel(const int* __restrict__ src, const int* __restrict__ dst,
                               int* __restrict__ cursor, int* __restrict__ csr_src, int E) {
    const int e = blockIdx.x * blockDim.x + threadIdx.x;
    if (e >= E) return;
    const int pos = atomicAdd(&cursor[dst[e]], 1);
    csr_src[pos] = src[e];
}

// ---------------- fused online-softmax aggregate + residual + bias (+ mish) ----------------
// NPB nodes per 256-thread block; C = H*D channels per node, one thread per channel.
template <int H, int D, bool ACT, int NPB>
__global__ void gat_fused_aggregate(const int* __restrict__ row_ptr, const int* __restrict__ csr_src,
                                    const float* __restrict__ el, const float* __restrict__ er,
                                    const float* __restrict__ feat, const float* __restrict__ res,
                                    const float* __restrict__ bias, float* __restrict__ out, int N) {
    constexpr int C = H * D;
    const int local = threadIdx.x % C;
    const int n = blockIdx.x * NPB + threadIdx.x / C;
    if (n >= N) return;
    const int h = local / D;
    const float erd = er[n * H + h];

    float m = -INFINITY, l = 0.f, acc = 0.f;
    const int pend = row_ptr[n + 1];
    for (int p = row_ptr[n]; p < pend; ++p) {
        const int s = csr_src[p];
        float e = el[s * H + h] + erd;
        e = (e >= 0.f) ? e : 0.2f * e;
        const float mn = fmaxf(m, e);
        const float sc = expf(m - mn);   // 0 on first iter (m = -inf)
        const float w = expf(e - mn);
        acc = acc * sc + w * feat[(long)s * C + local];
        l = l * sc + w;
        m = mn;
    }
    float v = ((l > 0.f) ? acc / l : 0.f) + res[(long)n * C + local] + bias[local];
    if (ACT) {
        float sp = (v > 20.f) ? v : log1pf(expf(v));
        v = v * tanhf(sp);
    }
    out[(long)n * C + local] = v;
}

// ---------------- host orchestration ----------------

static inline int cdiv(long a, long b) { return (int)((a + b - 1) / b); }

extern "C" void kernel_launch(void* const* d_in, const int* in_sizes, int n_in,
                              void* d_out, int out_size, void* d_ws, size_t ws_size,
                              hipStream_t stream) {
    const float* x   = (const float*)d_in[0];
    const int*   src = (const int*)d_in[1];
    const int*   dst = (const int*)d_in[2];
    const float* W0  = (const float*)d_in[3];
    const float* al0 = (const float*)d_in[4];
    const float* ar0 = (const float*)d_in[5];
    const float* b0  = (const float*)d_in[6];
    const float* W1  = (const float*)d_in[7];
    const float* al1 = (const float*)d_in[8];
    const float* ar1 = (const float*)d_in[9];
    const float* b1  = (const float*)d_in[10];
    const float* W2  = (const float*)d_in[11];
    const float* al2 = (const float*)d_in[12];
    const float* ar2 = (const float*)d_in[13];
    const float* b2  = (const float*)d_in[14];
    const float* rW2 = (const float*)d_in[15];
    float* out = (float*)d_out;

    const int N = in_sizes[0] / 256;   // 50000
    const int E = in_sizes[1];         // 800000
    const int K = 256;

    // workspace layout
    float* F     = (float*)d_ws;              // N*256 feat
    float* Hb    = F + (long)N * 256;         // N*256 hidden
    float* res2  = Hb + (long)N * 256;        // N*16
    float* el    = res2 + (long)N * 16;       // N*4
    float* er    = el + (long)N * 4;          // N*4
    int* deg     = (int*)(er + (long)N * 4);  // N
    int* row_ptr = deg + N;                   // N+1
    int* cursor  = row_ptr + N + 1;           // N
    int* csr_src = cursor + N;                // E

    const int THREADS = 256;
    dim3 gemm_grid(256 / 64, cdiv(N, 64));
    dim3 gemm16_grid(1, cdiv(N, 64));

    // ---------- CSR build (once; reused by all 3 layers) ----------
    hipMemsetAsync(deg, 0, (size_t)N * 4, stream);
    count_deg_kernel<<<cdiv(E, THREADS), THREADS, 0, stream>>>(dst, deg, E);
    exscan_kernel<<<1, 1024, 0, stream>>>(deg, row_ptr, N);
    copy_int_kernel<<<cdiv(N, THREADS), THREADS, 0, stream>>>(row_ptr, cursor, N);
    scatter_kernel<<<cdiv(E, THREADS), THREADS, 0, stream>>>(src, dst, cursor, csr_src, E);

    // ================= Layer 0 (H=4, D=64), input x, residual = x =================
    gemm_kernel<64, 64, 16, 4, 4><<<gemm_grid, 256, 0, stream>>>(x, W0, F, N, K, 256);
    el_er_kernel<4, 64><<<cdiv((long)N * 4 * 64, THREADS), THREADS, 0, stream>>>(F, al0, ar0, el, er, N);
    gat_fused_aggregate<4, 64, true, 1><<<N, 256, 0, stream>>>(row_ptr, csr_src, el, er, F, x, b0, Hb, N);

    // ================= Layer 1 (H=4, D=64), input Hb, residual = Hb ===============
    gemm_kernel<64, 64, 16, 4, 4><<<gemm_grid, 256, 0, stream>>>(Hb, W1, F, N, K, 256);
    el_er_kernel<4, 64><<<cdiv((long)N * 4 * 64, THREADS), THREADS, 0, stream>>>(F, al1, ar1, el, er, N);
    gat_fused_aggregate<4, 64, true, 1><<<N, 256, 0, stream>>>(row_ptr, csr_src, el, er, F, Hb, b1, Hb, N);

    // ================= Layer 2 (H=1, D=16), input Hb, residual = Hb @ rW2 =========
    gemm_kernel<64, 16, 16, 4, 4><<<gemm16_grid, 64, 0, stream>>>(Hb, W2, F, N, K, 16);
    gemm_kernel<64, 16, 16, 4, 4><<<gemm16_grid, 64, 0, stream>>>(Hb, rW2, res2, N, K, 16);
    el_er_kernel<1, 16><<<cdiv((long)N * 1 * 64, THREADS), THREADS, 0, stream>>>(F, al2, ar2, el, er, N);
    gat_fused_aggregate<1, 16, false, 16><<<cdiv(N, 16), 256, 0, stream>>>(row_ptr, csr_src, el, er, F, res2, b2, out, N);
}

// Round 3
// 1190.243 us; speedup vs baseline: 2.0213x; 1.2536x over previous
//
#include <hip/hip_runtime.h>
#include <cmath>

// ---------------- GEMM: C[N,M] = A[N,K] @ B[K,M] (row-major, fp32) ----------------
template <int BM, int BN, int BK, int TM, int TN>
__global__ void gemm_kernel(const float* __restrict__ A, const float* __restrict__ B,
                            float* __restrict__ C, int N, int K, int M) {
    constexpr int TX = BN / TN;
    constexpr int TY = BM / TM;
    constexpr int NT = TX * TY;
    __shared__ float As[BK][BM + 1];
    __shared__ float Bs[BK][BN + 1];

    const int tid = threadIdx.x;
    const int tx = tid % TX, ty = tid / TX;
    const int rowBase = blockIdx.y * BM;
    const int colBase = blockIdx.x * BN;

    float acc[TM][TN];
#pragma unroll
    for (int i = 0; i < TM; i++)
#pragma unroll
        for (int j = 0; j < TN; j++) acc[i][j] = 0.f;

    for (int k0 = 0; k0 < K; k0 += BK) {
        for (int idx = tid; idx < BM * BK; idx += NT) {
            int r = idx / BK, c = idx % BK;
            int gr = rowBase + r;
            As[c][r] = (gr < N) ? A[(long)gr * K + k0 + c] : 0.f;
        }
        for (int idx = tid; idx < BK * BN; idx += NT) {
            int r = idx / BN, c = idx % BN;
            Bs[r][c] = B[(long)(k0 + r) * M + colBase + c];
        }
        __syncthreads();
#pragma unroll
        for (int k = 0; k < BK; k++) {
            float a[TM], b[TN];
#pragma unroll
            for (int i = 0; i < TM; i++) a[i] = As[k][ty * TM + i];
#pragma unroll
            for (int j = 0; j < TN; j++) b[j] = Bs[k][tx * TN + j];
#pragma unroll
            for (int i = 0; i < TM; i++)
#pragma unroll
                for (int j = 0; j < TN; j++) acc[i][j] += a[i] * b[j];
        }
        __syncthreads();
    }
#pragma unroll
    for (int i = 0; i < TM; i++) {
        int gr = rowBase + ty * TM + i;
        if (gr < N) {
#pragma unroll
            for (int j = 0; j < TN; j++) {
                C[(long)gr * M + colBase + tx * TN + j] = acc[i][j];
            }
        }
    }
}

// ---------------- el/er: per (node, head) dot(feat, attn) ----------------
template <int H, int D>
__global__ void el_er_kernel(const float* __restrict__ feat,
                             const float* __restrict__ al, const float* __restrict__ ar,
                             float* __restrict__ el, float* __restrict__ er, int N) {
    const int wid = (blockIdx.x * blockDim.x + threadIdx.x) >> 6;
    const int lane = threadIdx.x & 63;
    if (wid >= N * H) return;
    const int n = wid / H, h = wid % H;
    float vl = 0.f, vr = 0.f;
    if (lane < D) {
        float f = feat[((long)n * H + h) * D + lane];
        vl = f * al[h * D + lane];
        vr = f * ar[h * D + lane];
    }
#pragma unroll
    for (int off = 32; off > 0; off >>= 1) {
        vl += __shfl_down(vl, off);
        vr += __shfl_down(vr, off);
    }
    if (lane == 0) { el[wid] = vl; er[wid] = vr; }
}

// ---------------- CSR build ----------------

__global__ void count_deg_kernel(const int* __restrict__ dst, int* __restrict__ deg, int E) {
    const int e = blockIdx.x * blockDim.x + threadIdx.x;
    if (e >= E) return;
    atomicAdd(&deg[dst[e]], 1);
}

__global__ void exscan_kernel(const int* __restrict__ deg, int* __restrict__ row_ptr, int N) {
    __shared__ int smem[1024];
    __shared__ int s_carry;
    const int tid = threadIdx.x;
    if (tid == 0) s_carry = 0;
    __syncthreads();
    for (int base = 0; base < N; base += 1024) {
        const int carry = s_carry;
        const int i = base + tid;
        const int v = (i < N) ? deg[i] : 0;
        smem[tid] = v;
        __syncthreads();
        int acc = v;
        for (int off = 1; off < 1024; off <<= 1) {
            const int t = (tid >= off) ? smem[tid - off] : 0;
            __syncthreads();
            acc += t;
            smem[tid] = acc;
            __syncthreads();
        }
        if (i < N) row_ptr[i] = carry + acc - v;
        if (tid == 1023) s_carry = carry + acc;
        __syncthreads();
    }
    if (tid == 0) row_ptr[N] = s_carry;
}

__global__ void copy_int_kernel(const int* __restrict__ a, int* __restrict__ b, int n) {
    const int i = blockIdx.x * blockDim.x + threadIdx.x;
    if (i < n) b[i] = a[i];
}

__global__ void scatter_kernel(const int* __restrict__ src, const int* __restrict__ dst,
                               int* __restrict__ cursor, int* __restrict__ csr_src, int E) {
    const int e = blockIdx.x * blockDim.x + threadIdx.x;
    if (e >= E) return;
    const int pos = atomicAdd(&cursor[dst[e]], 1);
    csr_src[pos] = src[e];
}

// ---------------- attention weights: one THREAD per (node, head) ----------------
// pass 1: max; pass 2: w = exp(e - max), store to attn, accumulate denom;
// pass 3: attn *= 1/denom. Softmax math done once per (edge, head), not per lane.
template <int H>
__global__ void attn_weight_kernel(const int* __restrict__ row_ptr, const int* __restrict__ csr_src,
                                   const float* __restrict__ el, const float* __restrict__ er,
                                   float* __restrict__ attn, int N) {
    const int t = blockIdx.x * blockDim.x + threadIdx.x;
    if (t >= N * H) return;
    const int n = t / H, h = t % H;
    const float erd = er[n * H + h];
    const int p0 = row_ptr[n], p1 = row_ptr[n + 1];
    float m = -INFINITY;
    for (int p = p0; p < p1; ++p) {
        float e = el[csr_src[p] * H + h] + erd;
        e = (e >= 0.f) ? e : 0.2f * e;
        m = fmaxf(m, e);
    }
    float denom = 0.f;
    for (int p = p0; p < p1; ++p) {
        float e = el[csr_src[p] * H + h] + erd;
        e = (e >= 0.f) ? e : 0.2f * e;
        const float w = expf(e - m);
        attn[p * H + h] = w;
        denom += w;
    }
    const float inv = (denom > 0.f) ? 1.f / denom : 0.f;
    for (int p = p0; p < p1; ++p) attn[p * H + h] *= inv;
}

// ---------------- aggregate: one WAVE per node, lane = 4 channels (float4) --------
// C = H*D = 256 channels -> 64 lanes x float4. Per edge: 1 broadcast index load,
// 1 attn load, 1 float4 gather, 4 FMAs.
template <int H, int D, bool ACT>
__global__ void gat_aggregate_wave(const int* __restrict__ row_ptr, const int* __restrict__ csr_src,
                                   const float* __restrict__ attn, const float* __restrict__ feat,
                                   const float* __restrict__ res, const float* __restrict__ bias,
                                   float* __restrict__ out, int N) {
    constexpr int C = H * D;       // 256
    constexpr int V = C / 4;       // 64 float4 per node row
    const int wave = threadIdx.x >> 6;
    const int lane = threadIdx.x & 63;
    const int n = blockIdx.x * (blockDim.x >> 6) + wave;
    if (n >= N) return;
    const int h = (lane * 4) / D;
    const float4* feat4 = (const float4*)feat;

    float4 acc = {0.f, 0.f, 0.f, 0.f};
    const int pend = row_ptr[n + 1];
    for (int p = row_ptr[n]; p < pend; ++p) {
        const int s = csr_src[p];
        const float w = attn[p * H + h];
        const float4 f = feat4[(long)s * V + lane];
        acc.x += w * f.x; acc.y += w * f.y; acc.z += w * f.z; acc.w += w * f.w;
    }
    const float4 r = ((const float4*)res)[(long)n * V + lane];
    const float4 bb = ((const float4*)bias)[lane];
    float v[4] = {acc.x + r.x + bb.x, acc.y + r.y + bb.y,
                  acc.z + r.z + bb.z, acc.w + r.w + bb.w};
    if (ACT) {
#pragma unroll
        for (int i = 0; i < 4; i++) {
            const float sp = (v[i] > 20.f) ? v[i] : log1pf(expf(v[i]));
            v[i] = v[i] * tanhf(sp);
        }
    }
    float4 o = {v[0], v[1], v[2], v[3]};
    ((float4*)out)[(long)n * V + lane] = o;
}

// ---------------- small-C aggregate (layer 2): thread per channel ----------------
template <int H, int D, bool ACT, int NPB>
__global__ void gat_aggregate_small(const int* __restrict__ row_ptr, const int* __restrict__ csr_src,
                                    const float* __restrict__ attn, const float* __restrict__ feat,
                                    const float* __restrict__ res, const float* __restrict__ bias,
                                    float* __restrict__ out, int N) {
    constexpr int C = H * D;
    const int local = threadIdx.x % C;
    const int n = blockIdx.x * NPB + threadIdx.x / C;
    if (n >= N) return;
    const int h = local / D;
    float acc = 0.f;
    const int pend = row_ptr[n + 1];
    for (int p = row_ptr[n]; p < pend; ++p) {
        const int s = csr_src[p];
        acc += attn[p * H + h] * feat[(long)s * C + local];
    }
    float v = acc + res[(long)n * C + local] + bias[local];
    if (ACT) {
        const float sp = (v > 20.f) ? v : log1pf(expf(v));
        v = v * tanhf(sp);
    }
    out[(long)n * C + local] = v;
}

// ---------------- host orchestration ----------------

static inline int cdiv(long a, long b) { return (int)((a + b - 1) / b); }

extern "C" void kernel_launch(void* const* d_in, const int* in_sizes, int n_in,
                              void* d_out, int out_size, void* d_ws, size_t ws_size,
                              hipStream_t stream) {
    const float* x   = (const float*)d_in[0];
    const int*   src = (const int*)d_in[1];
    const int*   dst = (const int*)d_in[2];
    const float* W0  = (const float*)d_in[3];
    const float* al0 = (const float*)d_in[4];
    const float* ar0 = (const float*)d_in[5];
    const float* b0  = (const float*)d_in[6];
    const float* W1  = (const float*)d_in[7];
    const float* al1 = (const float*)d_in[8];
    const float* ar1 = (const float*)d_in[9];
    const float* b1  = (const float*)d_in[10];
    const float* W2  = (const float*)d_in[11];
    const float* al2 = (const float*)d_in[12];
    const float* ar2 = (const float*)d_in[13];
    const float* b2  = (const float*)d_in[14];
    const float* rW2 = (const float*)d_in[15];
    float* out = (float*)d_out;

    const int N = in_sizes[0] / 256;   // 50000
    const int E = in_sizes[1];         // 800000
    const int K = 256;

    // workspace layout
    float* F     = (float*)d_ws;              // N*256 feat
    float* Hb    = F + (long)N * 256;         // N*256 hidden
    float* res2  = Hb + (long)N * 256;        // N*16
    float* el    = res2 + (long)N * 16;       // N*4
    float* er    = el + (long)N * 4;          // N*4
    float* attn  = er + (long)N * 4;          // E*4
    int* deg     = (int*)(attn + (long)E * 4);// N
    int* row_ptr = deg + N;                   // N+1
    int* cursor  = row_ptr + N + 1;           // N
    int* csr_src = cursor + N;                // E

    const int THREADS = 256;
    dim3 gemm_grid(256 / 64, cdiv(N, 64));
    dim3 gemm16_grid(1, cdiv(N, 64));

    // ---------- CSR build (once; reused by all 3 layers) ----------
    hipMemsetAsync(deg, 0, (size_t)N * 4, stream);
    count_deg_kernel<<<cdiv(E, THREADS), THREADS, 0, stream>>>(dst, deg, E);
    exscan_kernel<<<1, 1024, 0, stream>>>(deg, row_ptr, N);
    copy_int_kernel<<<cdiv(N, THREADS), THREADS, 0, stream>>>(row_ptr, cursor, N);
    scatter_kernel<<<cdiv(E, THREADS), THREADS, 0, stream>>>(src, dst, cursor, csr_src, E);

    // ================= Layer 0 (H=4, D=64), input x, residual = x =================
    gemm_kernel<64, 64, 16, 4, 4><<<gemm_grid, 256, 0, stream>>>(x, W0, F, N, K, 256);
    el_er_kernel<4, 64><<<cdiv((long)N * 4 * 64, THREADS), THREADS, 0, stream>>>(F, al0, ar0, el, er, N);
    attn_weight_kernel<4><<<cdiv((long)N * 4, THREADS), THREADS, 0, stream>>>(row_ptr, csr_src, el, er, attn, N);
    gat_aggregate_wave<4, 64, true><<<cdiv(N, 4), 256, 0, stream>>>(row_ptr, csr_src, attn, F, x, b0, Hb, N);

    // ================= Layer 1 (H=4, D=64), input Hb, residual = Hb ===============
    gemm_kernel<64, 64, 16, 4, 4><<<gemm_grid, 256, 0, stream>>>(Hb, W1, F, N, K, 256);
    el_er_kernel<4, 64><<<cdiv((long)N * 4 * 64, THREADS), THREADS, 0, stream>>>(F, al1, ar1, el, er, N);
    attn_weight_kernel<4><<<cdiv((long)N * 4, THREADS), THREADS, 0, stream>>>(row_ptr, csr_src, el, er, attn, N);
    gat_aggregate_wave<4, 64, true><<<cdiv(N, 4), 256, 0, stream>>>(row_ptr, csr_src, attn, F, Hb, b1, Hb, N);

    // ================= Layer 2 (H=1, D=16), input Hb, residual = Hb @ rW2 =========
    gemm_kernel<64, 16, 16, 4, 4><<<gemm16_grid, 64, 0, stream>>>(Hb, W2, F, N, K, 16);
    gemm_kernel<64, 16, 16, 4, 4><<<gemm16_grid, 64, 0, stream>>>(Hb, rW2, res2, N, K, 16);
    el_er_kernel<1, 16><<<cdiv((long)N * 1 * 64, THREADS), THREADS, 0, stream>>>(F, al2, ar2, el, er, N);
    attn_weight_kernel<1><<<cdiv((long)N, THREADS), THREADS, 0, stream>>>(row_ptr, csr_src, el, er, attn, N);
    gat_aggregate_small<1, 16, false, 16><<<cdiv(N, 16), 256, 0, stream>>>(row_ptr, csr_src, attn, F, res2, b2, out, N);
}

// Round 4
// 928.807 us; speedup vs baseline: 2.5903x; 1.2815x over previous
//
#include <hip/hip_runtime.h>
#include <cmath>

typedef __bf16 bf16;
typedef __attribute__((ext_vector_type(8))) __bf16 bf16x8;
typedef __attribute__((ext_vector_type(4))) float f32x4;

// ---------------- weight prep: W[K,M] fp32 -> Wt[M,K] bf16 ----------------
__global__ void transpose_cast_kernel(const float* __restrict__ W, bf16* __restrict__ Wt,
                                      int K, int M) {
    const int idx = blockIdx.x * blockDim.x + threadIdx.x;
    if (idx >= K * M) return;
    const int k = idx / M, m = idx % M;
    Wt[m * K + k] = (bf16)W[idx];
}

// ---------------- MFMA GEMM: C[N,256] = A[N,256](fp32) @ B(from Bt[256,256] bf16) ---
// BM=128, BN=128, BK=32. 256 threads = 4 waves, each wave computes a 64x64 quadrant
// via 4x4 grid of 16x16x32 bf16 MFMAs. A converted fp32->bf16 during staging.
__global__ __launch_bounds__(256) void gemm_mfma_bf16(const float* __restrict__ A,
                                                      const bf16* __restrict__ Bt,
                                                      float* __restrict__ C, int N) {
    constexpr int K = 256, BM = 128, BK = 32;
    constexpr int LDA = BK + 8;  // 40 bf16 = 80 B row stride: start banks cycle, 2-way max
    __shared__ bf16 As[BM * LDA];
    __shared__ bf16 Bs[BM * LDA];

    const int tid = threadIdx.x;
    const int wave = tid >> 6, lane = tid & 63;
    const int quad = lane >> 4, l16 = lane & 15;
    const int rowBase = blockIdx.y * BM;
    const int colBase = blockIdx.x * BM;  // BN == BM == 128
    const int m_base = (wave >> 1) * 64, n_base = (wave & 1) * 64;

    f32x4 acc[4][4] = {};

    const int sr = tid >> 1;             // staging row 0..127
    const int seg = (tid & 1) << 4;      // k offset 0 or 16

    for (int k0 = 0; k0 < K; k0 += BK) {
        // ---- stage A tile (fp32 -> bf16) ----
        {
            const int gr = rowBase + sr;
            float4 f0 = {0,0,0,0}, f1 = {0,0,0,0}, f2 = {0,0,0,0}, f3 = {0,0,0,0};
            if (gr < N) {
                const float4* Ag = (const float4*)(A + (long)gr * K + k0 + seg);
                f0 = Ag[0]; f1 = Ag[1]; f2 = Ag[2]; f3 = Ag[3];
            }
            bf16x8 p0, p1;
            p0[0] = (bf16)f0.x; p0[1] = (bf16)f0.y; p0[2] = (bf16)f0.z; p0[3] = (bf16)f0.w;
            p0[4] = (bf16)f1.x; p0[5] = (bf16)f1.y; p0[6] = (bf16)f1.z; p0[7] = (bf16)f1.w;
            p1[0] = (bf16)f2.x; p1[1] = (bf16)f2.y; p1[2] = (bf16)f2.z; p1[3] = (bf16)f2.w;
            p1[4] = (bf16)f3.x; p1[5] = (bf16)f3.y; p1[6] = (bf16)f3.z; p1[7] = (bf16)f3.w;
            *(bf16x8*)&As[sr * LDA + seg] = p0;
            *(bf16x8*)&As[sr * LDA + seg + 8] = p1;
        }
        // ---- stage B tile (already bf16, transposed: Bt[n][k]) ----
        {
            const bf16x8* Bg = (const bf16x8*)(Bt + (long)(colBase + sr) * K + k0 + seg);
            *(bf16x8*)&Bs[sr * LDA + seg] = Bg[0];
            *(bf16x8*)&Bs[sr * LDA + seg + 8] = Bg[1];
        }
        __syncthreads();

        bf16x8 af[4], bfr[4];
#pragma unroll
        for (int mi = 0; mi < 4; mi++)
            af[mi] = *(const bf16x8*)&As[(m_base + mi * 16 + l16) * LDA + quad * 8];
#pragma unroll
        for (int ni = 0; ni < 4; ni++)
            bfr[ni] = *(const bf16x8*)&Bs[(n_base + ni * 16 + l16) * LDA + quad * 8];
#pragma unroll
        for (int mi = 0; mi < 4; mi++)
#pragma unroll
            for (int ni = 0; ni < 4; ni++)
                acc[mi][ni] = __builtin_amdgcn_mfma_f32_16x16x32_bf16(af[mi], bfr[ni], acc[mi][ni], 0, 0, 0);
        __syncthreads();
    }

    // epilogue: C/D layout col=lane&15, row=quad*4+reg  [m89-verified]
#pragma unroll
    for (int mi = 0; mi < 4; mi++) {
#pragma unroll
        for (int r = 0; r < 4; r++) {
            const int grow = rowBase + m_base + mi * 16 + quad * 4 + r;
            if (grow < N) {
#pragma unroll
                for (int ni = 0; ni < 4; ni++) {
                    C[(long)grow * 256 + colBase + n_base + ni * 16 + l16] = acc[mi][ni][r];
                }
            }
        }
    }
}

// ---------------- fp32 GEMM (layer-2 small outputs) ----------------
template <int BM, int BN, int BK, int TM, int TN>
__global__ void gemm_kernel(const float* __restrict__ A, const float* __restrict__ B,
                            float* __restrict__ C, int N, int K, int M) {
    constexpr int TX = BN / TN;
    constexpr int TY = BM / TM;
    constexpr int NT = TX * TY;
    __shared__ float As[BK][BM + 1];
    __shared__ float Bs[BK][BN + 1];

    const int tid = threadIdx.x;
    const int tx = tid % TX, ty = tid / TX;
    const int rowBase = blockIdx.y * BM;
    const int colBase = blockIdx.x * BN;

    float acc[TM][TN];
#pragma unroll
    for (int i = 0; i < TM; i++)
#pragma unroll
        for (int j = 0; j < TN; j++) acc[i][j] = 0.f;

    for (int k0 = 0; k0 < K; k0 += BK) {
        for (int idx = tid; idx < BM * BK; idx += NT) {
            int r = idx / BK, c = idx % BK;
            int gr = rowBase + r;
            As[c][r] = (gr < N) ? A[(long)gr * K + k0 + c] : 0.f;
        }
        for (int idx = tid; idx < BK * BN; idx += NT) {
            int r = idx / BN, c = idx % BN;
            Bs[r][c] = B[(long)(k0 + r) * M + colBase + c];
        }
        __syncthreads();
#pragma unroll
        for (int k = 0; k < BK; k++) {
            float a[TM], b[TN];
#pragma unroll
            for (int i = 0; i < TM; i++) a[i] = As[k][ty * TM + i];
#pragma unroll
            for (int j = 0; j < TN; j++) b[j] = Bs[k][tx * TN + j];
#pragma unroll
            for (int i = 0; i < TM; i++)
#pragma unroll
                for (int j = 0; j < TN; j++) acc[i][j] += a[i] * b[j];
        }
        __syncthreads();
    }
#pragma unroll
    for (int i = 0; i < TM; i++) {
        int gr = rowBase + ty * TM + i;
        if (gr < N) {
#pragma unroll
            for (int j = 0; j < TN; j++) {
                C[(long)gr * M + colBase + tx * TN + j] = acc[i][j];
            }
        }
    }
}

// ---------------- el/er: per (node, head) dot(feat, attn) ----------------
template <int H, int D>
__global__ void el_er_kernel(const float* __restrict__ feat,
                             const float* __restrict__ al, const float* __restrict__ ar,
                             float* __restrict__ el, float* __restrict__ er, int N) {
    const int wid = (blockIdx.x * blockDim.x + threadIdx.x) >> 6;
    const int lane = threadIdx.x & 63;
    if (wid >= N * H) return;
    const int n = wid / H, h = wid % H;
    float vl = 0.f, vr = 0.f;
    if (lane < D) {
        float f = feat[((long)n * H + h) * D + lane];
        vl = f * al[h * D + lane];
        vr = f * ar[h * D + lane];
    }
#pragma unroll
    for (int off = 32; off > 0; off >>= 1) {
        vl += __shfl_down(vl, off);
        vr += __shfl_down(vr, off);
    }
    if (lane == 0) { el[wid] = vl; er[wid] = vr; }
}

// ---------------- CSR build ----------------

__global__ void count_deg_kernel(const int* __restrict__ dst, int* __restrict__ deg, int E) {
    const int e = blockIdx.x * blockDim.x + threadIdx.x;
    if (e >= E) return;
    atomicAdd(&deg[dst[e]], 1);
}

__global__ void exscan_kernel(const int* __restrict__ deg, int* __restrict__ row_ptr, int N) {
    __shared__ int smem[1024];
    __shared__ int s_carry;
    const int tid = threadIdx.x;
    if (tid == 0) s_carry = 0;
    __syncthreads();
    for (int base = 0; base < N; base += 1024) {
        const int carry = s_carry;
        const int i = base + tid;
        const int v = (i < N) ? deg[i] : 0;
        smem[tid] = v;
        __syncthreads();
        int acc = v;
        for (int off = 1; off < 1024; off <<= 1) {
            const int t = (tid >= off) ? smem[tid - off] : 0;
            __syncthreads();
            acc += t;
            smem[tid] = acc;
            __syncthreads();
        }
        if (i < N) row_ptr[i] = carry + acc - v;
        if (tid == 1023) s_carry = carry + acc;
        __syncthreads();
    }
    if (tid == 0) row_ptr[N] = s_carry;
}

__global__ void copy_int_kernel(const int* __restrict__ a, int* __restrict__ b, int n) {
    const int i = blockIdx.x * blockDim.x + threadIdx.x;
    if (i < n) b[i] = a[i];
}

__global__ void scatter_kernel(const int* __restrict__ src, const int* __restrict__ dst,
                               int* __restrict__ cursor, int* __restrict__ csr_src, int E) {
    const int e = blockIdx.x * blockDim.x + threadIdx.x;
    if (e >= E) return;
    const int pos = atomicAdd(&cursor[dst[e]], 1);
    csr_src[pos] = src[e];
}

// ---------------- attention weights: one THREAD per (node, head) ----------------
template <int H>
__global__ void attn_weight_kernel(const int* __restrict__ row_ptr, const int* __restrict__ csr_src,
                                   const float* __restrict__ el, const float* __restrict__ er,
                                   float* __restrict__ attn, int N) {
    const int t = blockIdx.x * blockDim.x + threadIdx.x;
    if (t >= N * H) return;
    const int n = t / H, h = t % H;
    const float erd = er[n * H + h];
    const int p0 = row_ptr[n], p1 = row_ptr[n + 1];
    float m = -INFINITY;
    for (int p = p0; p < p1; ++p) {
        float e = el[csr_src[p] * H + h] + erd;
        e = (e >= 0.f) ? e : 0.2f * e;
        m = fmaxf(m, e);
    }
    float denom = 0.f;
    for (int p = p0; p < p1; ++p) {
        float e = el[csr_src[p] * H + h] + erd;
        e = (e >= 0.f) ? e : 0.2f * e;
        const float w = expf(e - m);
        attn[p * H + h] = w;
        denom += w;
    }
    const float inv = (denom > 0.f) ? 1.f / denom : 0.f;
    for (int p = p0; p < p1; ++p) attn[p * H + h] *= inv;
}

// ---------------- aggregate: one WAVE per node, lane = 4 channels (float4) --------
template <int H, int D, bool ACT>
__global__ void gat_aggregate_wave(const int* __restrict__ row_ptr, const int* __restrict__ csr_src,
                                   const float* __restrict__ attn, const float* __restrict__ feat,
                                   const float* __restrict__ res, const float* __restrict__ bias,
                                   float* __restrict__ out, int N) {
    constexpr int C = H * D;       // 256
    constexpr int V = C / 4;       // 64 float4 per node row
    const int wave = threadIdx.x >> 6;
    const int lane = threadIdx.x & 63;
    const int n = blockIdx.x * (blockDim.x >> 6) + wave;
    if (n >= N) return;
    const int h = (lane * 4) / D;
    const float4* feat4 = (const float4*)feat;

    float4 acc = {0.f, 0.f, 0.f, 0.f};
    const int pend = row_ptr[n + 1];
    for (int p = row_ptr[n]; p < pend; ++p) {
        const int s = csr_src[p];
        const float w = attn[p * H + h];
        const float4 f = feat4[(long)s * V + lane];
        acc.x += w * f.x; acc.y += w * f.y; acc.z += w * f.z; acc.w += w * f.w;
    }
    const float4 r = ((const float4*)res)[(long)n * V + lane];
    const float4 bb = ((const float4*)bias)[lane];
    float v[4] = {acc.x + r.x + bb.x, acc.y + r.y + bb.y,
                  acc.z + r.z + bb.z, acc.w + r.w + bb.w};
    if (ACT) {
#pragma unroll
        for (int i = 0; i < 4; i++) {
            const float sp = (v[i] > 20.f) ? v[i] : log1pf(expf(v[i]));
            v[i] = v[i] * tanhf(sp);
        }
    }
    float4 o = {v[0], v[1], v[2], v[3]};
    ((float4*)out)[(long)n * V + lane] = o;
}

// ---------------- small-C aggregate (layer 2): thread per channel ----------------
template <int H, int D, bool ACT, int NPB>
__global__ void gat_aggregate_small(const int* __restrict__ row_ptr, const int* __restrict__ csr_src,
                                    const float* __restrict__ attn, const float* __restrict__ feat,
                                    const float* __restrict__ res, const float* __restrict__ bias,
                                    float* __restrict__ out, int N) {
    constexpr int C = H * D;
    const int local = threadIdx.x % C;
    const int n = blockIdx.x * NPB + threadIdx.x / C;
    if (n >= N) return;
    const int h = local / D;
    float acc = 0.f;
    const int pend = row_ptr[n + 1];
    for (int p = row_ptr[n]; p < pend; ++p) {
        const int s = csr_src[p];
        acc += attn[p * H + h] * feat[(long)s * C + local];
    }
    float v = acc + res[(long)n * C + local] + bias[local];
    if (ACT) {
        const float sp = (v > 20.f) ? v : log1pf(expf(v));
        v = v * tanhf(sp);
    }
    out[(long)n * C + local] = v;
}

// ---------------- host orchestration ----------------

static inline int cdiv(long a, long b) { return (int)((a + b - 1) / b); }

extern "C" void kernel_launch(void* const* d_in, const int* in_sizes, int n_in,
                              void* d_out, int out_size, void* d_ws, size_t ws_size,
                              hipStream_t stream) {
    const float* x   = (const float*)d_in[0];
    const int*   src = (const int*)d_in[1];
    const int*   dst = (const int*)d_in[2];
    const float* W0  = (const float*)d_in[3];
    const float* al0 = (const float*)d_in[4];
    const float* ar0 = (const float*)d_in[5];
    const float* b0  = (const float*)d_in[6];
    const float* W1  = (const float*)d_in[7];
    const float* al1 = (const float*)d_in[8];
    const float* ar1 = (const float*)d_in[9];
    const float* b1  = (const float*)d_in[10];
    const float* W2  = (const float*)d_in[11];
    const float* al2 = (const float*)d_in[12];
    const float* ar2 = (const float*)d_in[13];
    const float* b2  = (const float*)d_in[14];
    const float* rW2 = (const float*)d_in[15];
    float* out = (float*)d_out;

    const int N = in_sizes[0] / 256;   // 50000
    const int E = in_sizes[1];         // 800000
    const int K = 256;

    // workspace layout (bf16 weight buffers first for 16B alignment)
    bf16* Wt0    = (bf16*)d_ws;               // 256*256 bf16
    bf16* Wt1    = Wt0 + 65536;               // 256*256 bf16
    float* F     = (float*)(Wt1 + 65536);     // N*256 feat
    float* Hb    = F + (long)N * 256;         // N*256 hidden
    float* res2  = Hb + (long)N * 256;        // N*16
    float* el    = res2 + (long)N * 16;       // N*4
    float* er    = el + (long)N * 4;          // N*4
    float* attn  = er + (long)N * 4;          // E*4
    int* deg     = (int*)(attn + (long)E * 4);// N
    int* row_ptr = deg + N;                   // N+1
    int* cursor  = row_ptr + N + 1;           // N
    int* csr_src = cursor + N;                // E

    const int THREADS = 256;
    dim3 mfma_grid(2, cdiv(N, 128));
    dim3 gemm16_grid(1, cdiv(N, 64));

    // ---------- weight prep + CSR build (reused by all layers) ----------
    transpose_cast_kernel<<<cdiv(65536, THREADS), THREADS, 0, stream>>>(W0, Wt0, K, 256);
    transpose_cast_kernel<<<cdiv(65536, THREADS), THREADS, 0, stream>>>(W1, Wt1, K, 256);
    hipMemsetAsync(deg, 0, (size_t)N * 4, stream);
    count_deg_kernel<<<cdiv(E, THREADS), THREADS, 0, stream>>>(dst, deg, E);
    exscan_kernel<<<1, 1024, 0, stream>>>(deg, row_ptr, N);
    copy_int_kernel<<<cdiv(N, THREADS), THREADS, 0, stream>>>(row_ptr, cursor, N);
    scatter_kernel<<<cdiv(E, THREADS), THREADS, 0, stream>>>(src, dst, cursor, csr_src, E);

    // ================= Layer 0 (H=4, D=64), input x, residual = x =================
    gemm_mfma_bf16<<<mfma_grid, 256, 0, stream>>>(x, Wt0, F, N);
    el_er_kernel<4, 64><<<cdiv((long)N * 4 * 64, THREADS), THREADS, 0, stream>>>(F, al0, ar0, el, er, N);
    attn_weight_kernel<4><<<cdiv((long)N * 4, THREADS), THREADS, 0, stream>>>(row_ptr, csr_src, el, er, attn, N);
    gat_aggregate_wave<4, 64, true><<<cdiv(N, 4), 256, 0, stream>>>(row_ptr, csr_src, attn, F, x, b0, Hb, N);

    // ================= Layer 1 (H=4, D=64), input Hb, residual = Hb ===============
    gemm_mfma_bf16<<<mfma_grid, 256, 0, stream>>>(Hb, Wt1, F, N);
    el_er_kernel<4, 64><<<cdiv((long)N * 4 * 64, THREADS), THREADS, 0, stream>>>(F, al1, ar1, el, er, N);
    attn_weight_kernel<4><<<cdiv((long)N * 4, THREADS), THREADS, 0, stream>>>(row_ptr, csr_src, el, er, attn, N);
    gat_aggregate_wave<4, 64, true><<<cdiv(N, 4), 256, 0, stream>>>(row_ptr, csr_src, attn, F, Hb, b1, Hb, N);

    // ================= Layer 2 (H=1, D=16), input Hb, residual = Hb @ rW2 =========
    gemm_kernel<64, 16, 16, 4, 4><<<gemm16_grid, 64, 0, stream>>>(Hb, W2, F, N, K, 16);
    gemm_kernel<64, 16, 16, 4, 4><<<gemm16_grid, 64, 0, stream>>>(Hb, rW2, res2, N, K, 16);
    el_er_kernel<1, 16><<<cdiv((long)N * 1 * 64, THREADS), THREADS, 0, stream>>>(F, al2, ar2, el, er, N);
    attn_weight_kernel<1><<<cdiv((long)N, THREADS), THREADS, 0, stream>>>(row_ptr, csr_src, el, er, attn, N);
    gat_aggregate_small<1, 16, false, 16><<<cdiv(N, 16), 256, 0, stream>>>(row_ptr, csr_src, attn, F, res2, b2, out, N);
}

// Round 5
// 789.756 us; speedup vs baseline: 3.0463x; 1.1761x over previous
//
#include <hip/hip_runtime.h>
#include <cmath>

typedef __bf16 bf16;
typedef __attribute__((ext_vector_type(8))) __bf16 bf16x8;
typedef __attribute__((ext_vector_type(4))) __bf16 bf16x4;
typedef __attribute__((ext_vector_type(4))) float f32x4;

// ---------------- weight prep: W[K,M] fp32 -> Wt[M,K] bf16 ----------------
__global__ void transpose_cast_kernel(const float* __restrict__ W, bf16* __restrict__ Wt,
                                      int K, int M) {
    const int idx = blockIdx.x * blockDim.x + threadIdx.x;
    if (idx >= K * M) return;
    const int k = idx / M, m = idx % M;
    Wt[m * K + k] = (bf16)W[idx];
}

// concat W2[256,16] | rW2[256,16] -> Bc[256,32]
__global__ void concat_w2_kernel(const float* __restrict__ W2, const float* __restrict__ rW2,
                                 float* __restrict__ Bc) {
    const int idx = blockIdx.x * blockDim.x + threadIdx.x;
    if (idx >= 256 * 32) return;
    const int k = idx / 32, m = idx % 32;
    Bc[idx] = (m < 16) ? W2[k * 16 + m] : rW2[k * 16 + (m - 16)];
}

// ---------------- MFMA GEMM: Fb[N,256](bf16) = A[N,256](fp32) @ B (Bt bf16) ----
__global__ __launch_bounds__(256) void gemm_mfma_bf16(const float* __restrict__ A,
                                                      const bf16* __restrict__ Bt,
                                                      bf16* __restrict__ Fb, int N) {
    constexpr int K = 256, BM = 128, BK = 32;
    constexpr int LDA = BK + 8;
    __shared__ bf16 As[BM * LDA];
    __shared__ bf16 Bs[BM * LDA];

    const int tid = threadIdx.x;
    const int wave = tid >> 6, lane = tid & 63;
    const int quad = lane >> 4, l16 = lane & 15;
    const int rowBase = blockIdx.y * BM;
    const int colBase = blockIdx.x * BM;
    const int m_base = (wave >> 1) * 64, n_base = (wave & 1) * 64;

    f32x4 acc[4][4] = {};

    const int sr = tid >> 1;
    const int seg = (tid & 1) << 4;

    for (int k0 = 0; k0 < K; k0 += BK) {
        {
            const int gr = rowBase + sr;
            float4 f0 = {0,0,0,0}, f1 = {0,0,0,0}, f2 = {0,0,0,0}, f3 = {0,0,0,0};
            if (gr < N) {
                const float4* Ag = (const float4*)(A + (long)gr * K + k0 + seg);
                f0 = Ag[0]; f1 = Ag[1]; f2 = Ag[2]; f3 = Ag[3];
            }
            bf16x8 p0, p1;
            p0[0] = (bf16)f0.x; p0[1] = (bf16)f0.y; p0[2] = (bf16)f0.z; p0[3] = (bf16)f0.w;
            p0[4] = (bf16)f1.x; p0[5] = (bf16)f1.y; p0[6] = (bf16)f1.z; p0[7] = (bf16)f1.w;
            p1[0] = (bf16)f2.x; p1[1] = (bf16)f2.y; p1[2] = (bf16)f2.z; p1[3] = (bf16)f2.w;
            p1[4] = (bf16)f3.x; p1[5] = (bf16)f3.y; p1[6] = (bf16)f3.z; p1[7] = (bf16)f3.w;
            *(bf16x8*)&As[sr * LDA + seg] = p0;
            *(bf16x8*)&As[sr * LDA + seg + 8] = p1;
        }
        {
            const bf16x8* Bg = (const bf16x8*)(Bt + (long)(colBase + sr) * K + k0 + seg);
            *(bf16x8*)&Bs[sr * LDA + seg] = Bg[0];
            *(bf16x8*)&Bs[sr * LDA + seg + 8] = Bg[1];
        }
        __syncthreads();

        bf16x8 af[4], bfr[4];
#pragma unroll
        for (int mi = 0; mi < 4; mi++)
            af[mi] = *(const bf16x8*)&As[(m_base + mi * 16 + l16) * LDA + quad * 8];
#pragma unroll
        for (int ni = 0; ni < 4; ni++)
            bfr[ni] = *(const bf16x8*)&Bs[(n_base + ni * 16 + l16) * LDA + quad * 8];
#pragma unroll
        for (int mi = 0; mi < 4; mi++)
#pragma unroll
            for (int ni = 0; ni < 4; ni++)
                acc[mi][ni] = __builtin_amdgcn_mfma_f32_16x16x32_bf16(af[mi], bfr[ni], acc[mi][ni], 0, 0, 0);
        __syncthreads();
    }

    // epilogue: C/D layout col=lane&15, row=quad*4+reg  [m89-verified]; write bf16
#pragma unroll
    for (int mi = 0; mi < 4; mi++) {
#pragma unroll
        for (int r = 0; r < 4; r++) {
            const int grow = rowBase + m_base + mi * 16 + quad * 4 + r;
            if (grow < N) {
#pragma unroll
                for (int ni = 0; ni < 4; ni++) {
                    Fb[(long)grow * 256 + colBase + n_base + ni * 16 + l16] = (bf16)acc[mi][ni][r];
                }
            }
        }
    }
}

// ---------------- fp32 GEMM (layer-2 combined W2|rW2) ----------------
template <int BM, int BN, int BK, int TM, int TN>
__global__ void gemm_kernel(const float* __restrict__ A, const float* __restrict__ B,
                            float* __restrict__ C, int N, int K, int M) {
    constexpr int TX = BN / TN;
    constexpr int TY = BM / TM;
    constexpr int NT = TX * TY;
    __shared__ float As[BK][BM + 1];
    __shared__ float Bs[BK][BN + 1];

    const int tid = threadIdx.x;
    const int tx = tid % TX, ty = tid / TX;
    const int rowBase = blockIdx.y * BM;
    const int colBase = blockIdx.x * BN;

    float acc[TM][TN];
#pragma unroll
    for (int i = 0; i < TM; i++)
#pragma unroll
        for (int j = 0; j < TN; j++) acc[i][j] = 0.f;

    for (int k0 = 0; k0 < K; k0 += BK) {
        for (int idx = tid; idx < BM * BK; idx += NT) {
            int r = idx / BK, c = idx % BK;
            int gr = rowBase + r;
            As[c][r] = (gr < N) ? A[(long)gr * K + k0 + c] : 0.f;
        }
        for (int idx = tid; idx < BK * BN; idx += NT) {
            int r = idx / BN, c = idx % BN;
            Bs[r][c] = B[(long)(k0 + r) * M + colBase + c];
        }
        __syncthreads();
#pragma unroll
        for (int k = 0; k < BK; k++) {
            float a[TM], b[TN];
#pragma unroll
            for (int i = 0; i < TM; i++) a[i] = As[k][ty * TM + i];
#pragma unroll
            for (int j = 0; j < TN; j++) b[j] = Bs[k][tx * TN + j];
#pragma unroll
            for (int i = 0; i < TM; i++)
#pragma unroll
                for (int j = 0; j < TN; j++) acc[i][j] += a[i] * b[j];
        }
        __syncthreads();
    }
#pragma unroll
    for (int i = 0; i < TM; i++) {
        int gr = rowBase + ty * TM + i;
        if (gr < N) {
#pragma unroll
            for (int j = 0; j < TN; j++) {
                C[(long)gr * M + colBase + tx * TN + j] = acc[i][j];
            }
        }
    }
}

// ---------------- el/er from bf16 feat ----------------
template <int H, int D>
__global__ void el_er_kernel_bf16(const bf16* __restrict__ feat,
                                  const float* __restrict__ al, const float* __restrict__ ar,
                                  float* __restrict__ el, float* __restrict__ er, int N) {
    const int wid = (blockIdx.x * blockDim.x + threadIdx.x) >> 6;
    const int lane = threadIdx.x & 63;
    if (wid >= N * H) return;
    const int n = wid / H, h = wid % H;
    float vl = 0.f, vr = 0.f;
    if (lane < D) {
        float f = (float)feat[((long)n * H + h) * D + lane];
        vl = f * al[h * D + lane];
        vr = f * ar[h * D + lane];
    }
#pragma unroll
    for (int off = 32; off > 0; off >>= 1) {
        vl += __shfl_down(vl, off);
        vr += __shfl_down(vr, off);
    }
    if (lane == 0) { el[wid] = vl; er[wid] = vr; }
}

// el/er from fp32 feat with row stride (layer 2)
template <int H, int D>
__global__ void el_er_strided(const float* __restrict__ feat, int stride,
                              const float* __restrict__ al, const float* __restrict__ ar,
                              float* __restrict__ el, float* __restrict__ er, int N) {
    const int wid = (blockIdx.x * blockDim.x + threadIdx.x) >> 6;
    const int lane = threadIdx.x & 63;
    if (wid >= N * H) return;
    const int n = wid / H, h = wid % H;
    float vl = 0.f, vr = 0.f;
    if (lane < D) {
        float f = feat[(long)n * stride + h * D + lane];
        vl = f * al[h * D + lane];
        vr = f * ar[h * D + lane];
    }
#pragma unroll
    for (int off = 32; off > 0; off >>= 1) {
        vl += __shfl_down(vl, off);
        vr += __shfl_down(vr, off);
    }
    if (lane == 0) { el[wid] = vl; er[wid] = vr; }
}

// ---------------- CSR build ----------------

__global__ void count_deg_kernel(const int* __restrict__ dst, int* __restrict__ deg, int E) {
    const int e = blockIdx.x * blockDim.x + threadIdx.x;
    if (e >= E) return;
    atomicAdd(&deg[dst[e]], 1);
}

__global__ void exscan_kernel(const int* __restrict__ deg, int* __restrict__ row_ptr, int N) {
    __shared__ int smem[1024];
    __shared__ int s_carry;
    const int tid = threadIdx.x;
    if (tid == 0) s_carry = 0;
    __syncthreads();
    for (int base = 0; base < N; base += 1024) {
        const int carry = s_carry;
        const int i = base + tid;
        const int v = (i < N) ? deg[i] : 0;
        smem[tid] = v;
        __syncthreads();
        int acc = v;
        for (int off = 1; off < 1024; off <<= 1) {
            const int t = (tid >= off) ? smem[tid - off] : 0;
            __syncthreads();
            acc += t;
            smem[tid] = acc;
            __syncthreads();
        }
        if (i < N) row_ptr[i] = carry + acc - v;
        if (tid == 1023) s_carry = carry + acc;
        __syncthreads();
    }
    if (tid == 0) row_ptr[N] = s_carry;
}

__global__ void copy_int_kernel(const int* __restrict__ a, int* __restrict__ b, int n) {
    const int i = blockIdx.x * blockDim.x + threadIdx.x;
    if (i < n) b[i] = a[i];
}

__global__ void scatter_kernel(const int* __restrict__ src, const int* __restrict__ dst,
                               int* __restrict__ cursor, int* __restrict__ csr_src, int E) {
    const int e = blockIdx.x * blockDim.x + threadIdx.x;
    if (e >= E) return;
    const int pos = atomicAdd(&cursor[dst[e]], 1);
    csr_src[pos] = src[e];
}

// ---------------- attention weights: one THREAD per (node, head) ----------------
// pass 1: compute e, stash in attn, track max; pass 2: w = exp(e-m), denom; pass 3: scale.
template <int H>
__global__ void attn_weight_kernel(const int* __restrict__ row_ptr, const int* __restrict__ csr_src,
                                   const float* __restrict__ el, const float* __restrict__ er,
                                   float* __restrict__ attn, int N) {
    const int t = blockIdx.x * blockDim.x + threadIdx.x;
    if (t >= N * H) return;
    const int n = t / H, h = t % H;
    const float erd = er[n * H + h];
    const int p0 = row_ptr[n], p1 = row_ptr[n + 1];
    float m = -INFINITY;
    for (int p = p0; p < p1; ++p) {
        float e = el[csr_src[p] * H + h] + erd;
        e = (e >= 0.f) ? e : 0.2f * e;
        attn[p * H + h] = e;
        m = fmaxf(m, e);
    }
    float denom = 0.f;
    for (int p = p0; p < p1; ++p) {
        const float w = expf(attn[p * H + h] - m);
        attn[p * H + h] = w;
        denom += w;
    }
    const float inv = (denom > 0.f) ? 1.f / denom : 0.f;
    for (int p = p0; p < p1; ++p) attn[p * H + h] *= inv;
}

// ---------------- aggregate: one WAVE per node, lane = 4 bf16 channels ----------
template <int H, int D, bool ACT>
__global__ void gat_aggregate_wave(const int* __restrict__ row_ptr, const int* __restrict__ csr_src,
                                   const float* __restrict__ attn, const bf16* __restrict__ feat,
                                   const float* __restrict__ res, const float* __restrict__ bias,
                                   float* __restrict__ out, int N) {
    constexpr int C = H * D;       // 256
    constexpr int V = C / 4;       // 64 bf16x4 per node row
    const int wave = threadIdx.x >> 6;
    const int lane = threadIdx.x & 63;
    const int n = blockIdx.x * (blockDim.x >> 6) + wave;
    if (n >= N) return;
    const int h = (lane * 4) / D;
    const bf16x4* feat4 = (const bf16x4*)feat;

    float4 acc = {0.f, 0.f, 0.f, 0.f};
    const int pend = row_ptr[n + 1];
    for (int p = row_ptr[n]; p < pend; ++p) {
        const int s = csr_src[p];
        const float w = attn[p * H + h];
        const bf16x4 f = feat4[(long)s * V + lane];
        acc.x += w * (float)f[0];
        acc.y += w * (float)f[1];
        acc.z += w * (float)f[2];
        acc.w += w * (float)f[3];
    }
    const float4 r = ((const float4*)res)[(long)n * V + lane];
    const float4 bb = ((const float4*)bias)[lane];
    float v[4] = {acc.x + r.x + bb.x, acc.y + r.y + bb.y,
                  acc.z + r.z + bb.z, acc.w + r.w + bb.w};
    if (ACT) {
#pragma unroll
        for (int i = 0; i < 4; i++) {
            const float sp = (v[i] > 20.f) ? v[i] : log1pf(expf(v[i]));
            v[i] = v[i] * tanhf(sp);
        }
    }
    float4 o = {v[0], v[1], v[2], v[3]};
    ((float4*)out)[(long)n * V + lane] = o;
}

// ---------------- small-C aggregate (layer 2): thread per channel, strided -------
template <int H, int D, bool ACT, int NPB>
__global__ void gat_aggregate_small(const int* __restrict__ row_ptr, const int* __restrict__ csr_src,
                                    const float* __restrict__ attn,
                                    const float* __restrict__ feat, int fstride,
                                    const float* __restrict__ res, int rstride,
                                    const float* __restrict__ bias, float* __restrict__ out, int N) {
    constexpr int C = H * D;
    const int local = threadIdx.x % C;
    const int n = blockIdx.x * NPB + threadIdx.x / C;
    if (n >= N) return;
    const int h = local / D;
    float acc = 0.f;
    const int pend = row_ptr[n + 1];
    for (int p = row_ptr[n]; p < pend; ++p) {
        const int s = csr_src[p];
        acc += attn[p * H + h] * feat[(long)s * fstride + local];
    }
    float v = acc + res[(long)n * rstride + local] + bias[local];
    if (ACT) {
        const float sp = (v > 20.f) ? v : log1pf(expf(v));
        v = v * tanhf(sp);
    }
    out[(long)n * C + local] = v;
}

// ---------------- host orchestration ----------------

static inline int cdiv(long a, long b) { return (int)((a + b - 1) / b); }

extern "C" void kernel_launch(void* const* d_in, const int* in_sizes, int n_in,
                              void* d_out, int out_size, void* d_ws, size_t ws_size,
                              hipStream_t stream) {
    const float* x   = (const float*)d_in[0];
    const int*   src = (const int*)d_in[1];
    const int*   dst = (const int*)d_in[2];
    const float* W0  = (const float*)d_in[3];
    const float* al0 = (const float*)d_in[4];
    const float* ar0 = (const float*)d_in[5];
    const float* b0  = (const float*)d_in[6];
    const float* W1  = (const float*)d_in[7];
    const float* al1 = (const float*)d_in[8];
    const float* ar1 = (const float*)d_in[9];
    const float* b1  = (const float*)d_in[10];
    const float* W2  = (const float*)d_in[11];
    const float* al2 = (const float*)d_in[12];
    const float* ar2 = (const float*)d_in[13];
    const float* b2  = (const float*)d_in[14];
    const float* rW2 = (const float*)d_in[15];
    float* out = (float*)d_out;

    const int N = in_sizes[0] / 256;   // 50000
    const int E = in_sizes[1];         // 800000
    const int K = 256;

    // workspace layout
    bf16* Wt0    = (bf16*)d_ws;               // 256*256 bf16
    bf16* Wt1    = Wt0 + 65536;               // 256*256 bf16
    bf16* Fb     = Wt1 + 65536;               // N*256 bf16 feat
    float* Bc    = (float*)(Fb + (long)N * 256);  // 256*32 combined W2|rW2
    float* F2    = Bc + 256 * 32;             // N*32 (layer2 feat | res)
    float* Hb    = F2 + (long)N * 32;         // N*256 hidden (fp32)
    float* el    = Hb + (long)N * 256;        // N*4
    float* er    = el + (long)N * 4;          // N*4
    float* attn  = er + (long)N * 4;          // E*4
    int* deg     = (int*)(attn + (long)E * 4);// N
    int* row_ptr = deg + N;                   // N+1
    int* cursor  = row_ptr + N + 1;           // N
    int* csr_src = cursor + N;                // E

    const int THREADS = 256;
    dim3 mfma_grid(2, cdiv(N, 128));
    dim3 gemm32_grid(1, cdiv(N, 64));

    // ---------- weight prep + CSR build (reused by all layers) ----------
    transpose_cast_kernel<<<cdiv(65536, THREADS), THREADS, 0, stream>>>(W0, Wt0, K, 256);
    transpose_cast_kernel<<<cdiv(65536, THREADS), THREADS, 0, stream>>>(W1, Wt1, K, 256);
    concat_w2_kernel<<<cdiv(256 * 32, THREADS), THREADS, 0, stream>>>(W2, rW2, Bc);
    hipMemsetAsync(deg, 0, (size_t)N * 4, stream);
    count_deg_kernel<<<cdiv(E, THREADS), THREADS, 0, stream>>>(dst, deg, E);
    exscan_kernel<<<1, 1024, 0, stream>>>(deg, row_ptr, N);
    copy_int_kernel<<<cdiv(N, THREADS), THREADS, 0, stream>>>(row_ptr, cursor, N);
    scatter_kernel<<<cdiv(E, THREADS), THREADS, 0, stream>>>(src, dst, cursor, csr_src, E);

    // ================= Layer 0 (H=4, D=64), input x, residual = x =================
    gemm_mfma_bf16<<<mfma_grid, 256, 0, stream>>>(x, Wt0, Fb, N);
    el_er_kernel_bf16<4, 64><<<cdiv((long)N * 4 * 64, THREADS), THREADS, 0, stream>>>(Fb, al0, ar0, el, er, N);
    attn_weight_kernel<4><<<cdiv((long)N * 4, THREADS), THREADS, 0, stream>>>(row_ptr, csr_src, el, er, attn, N);
    gat_aggregate_wave<4, 64, true><<<cdiv(N, 4), 256, 0, stream>>>(row_ptr, csr_src, attn, Fb, x, b0, Hb, N);

    // ================= Layer 1 (H=4, D=64), input Hb, residual = Hb ===============
    gemm_mfma_bf16<<<mfma_grid, 256, 0, stream>>>(Hb, Wt1, Fb, N);
    el_er_kernel_bf16<4, 64><<<cdiv((long)N * 4 * 64, THREADS), THREADS, 0, stream>>>(Fb, al1, ar1, el, er, N);
    attn_weight_kernel<4><<<cdiv((long)N * 4, THREADS), THREADS, 0, stream>>>(row_ptr, csr_src, el, er, attn, N);
    gat_aggregate_wave<4, 64, true><<<cdiv(N, 4), 256, 0, stream>>>(row_ptr, csr_src, attn, Fb, Hb, b1, Hb, N);

    // ================= Layer 2 (H=1, D=16): F2 = Hb @ [W2|rW2] =====================
    gemm_kernel<64, 32, 16, 4, 4><<<gemm32_grid, 128, 0, stream>>>(Hb, Bc, F2, N, K, 32);
    el_er_strided<1, 16><<<cdiv((long)N * 64, THREADS), THREADS, 0, stream>>>(F2, 32, al2, ar2, el, er, N);
    attn_weight_kernel<1><<<cdiv((long)N, THREADS), THREADS, 0, stream>>>(row_ptr, csr_src, el, er, attn, N);
    gat_aggregate_small<1, 16, false, 16><<<cdiv(N, 16), 256, 0, stream>>>(row_ptr, csr_src, attn,
                                                                           F2, 32, F2 + 16, 32, b2, out, N);
}

// Round 6
// 643.838 us; speedup vs baseline: 3.7368x; 1.2266x over previous
//
#include <hip/hip_runtime.h>
#include <cmath>

typedef __bf16 bf16;
typedef __attribute__((ext_vector_type(8))) __bf16 bf16x8;
typedef __attribute__((ext_vector_type(4))) __bf16 bf16x4;
typedef __attribute__((ext_vector_type(4))) float f32x4;

// ---------------- weight prep: W[K,M] fp32 -> Wt[M,K] bf16 ----------------
__global__ void transpose_cast_kernel(const float* __restrict__ W, bf16* __restrict__ Wt,
                                      int K, int M) {
    const int idx = blockIdx.x * blockDim.x + threadIdx.x;
    if (idx >= K * M) return;
    const int k = idx / M, m = idx % M;
    Wt[m * K + k] = (bf16)W[idx];
}

// concat W2[256,16] | rW2[256,16] -> Bc[256,32]
__global__ void concat_w2_kernel(const float* __restrict__ W2, const float* __restrict__ rW2,
                                 float* __restrict__ Bc) {
    const int idx = blockIdx.x * blockDim.x + threadIdx.x;
    if (idx >= 256 * 32) return;
    const int k = idx / 32, m = idx % 32;
    Bc[idx] = (m < 16) ? W2[k * 16 + m] : rW2[k * 16 + (m - 16)];
}

// ---------------- MFMA GEMM: Fb[N,256](bf16) = A[N,256](fp32) @ B (Bt bf16) ----
__global__ __launch_bounds__(256) void gemm_mfma_bf16(const float* __restrict__ A,
                                                      const bf16* __restrict__ Bt,
                                                      bf16* __restrict__ Fb, int N) {
    constexpr int K = 256, BM = 128, BK = 32;
    constexpr int LDA = BK + 8;
    __shared__ bf16 As[BM * LDA];
    __shared__ bf16 Bs[BM * LDA];

    const int tid = threadIdx.x;
    const int wave = tid >> 6, lane = tid & 63;
    const int quad = lane >> 4, l16 = lane & 15;
    const int rowBase = blockIdx.y * BM;
    const int colBase = blockIdx.x * BM;
    const int m_base = (wave >> 1) * 64, n_base = (wave & 1) * 64;

    f32x4 acc[4][4] = {};

    const int sr = tid >> 1;
    const int seg = (tid & 1) << 4;

    for (int k0 = 0; k0 < K; k0 += BK) {
        {
            const int gr = rowBase + sr;
            float4 f0 = {0,0,0,0}, f1 = {0,0,0,0}, f2 = {0,0,0,0}, f3 = {0,0,0,0};
            if (gr < N) {
                const float4* Ag = (const float4*)(A + (long)gr * K + k0 + seg);
                f0 = Ag[0]; f1 = Ag[1]; f2 = Ag[2]; f3 = Ag[3];
            }
            bf16x8 p0, p1;
            p0[0] = (bf16)f0.x; p0[1] = (bf16)f0.y; p0[2] = (bf16)f0.z; p0[3] = (bf16)f0.w;
            p0[4] = (bf16)f1.x; p0[5] = (bf16)f1.y; p0[6] = (bf16)f1.z; p0[7] = (bf16)f1.w;
            p1[0] = (bf16)f2.x; p1[1] = (bf16)f2.y; p1[2] = (bf16)f2.z; p1[3] = (bf16)f2.w;
            p1[4] = (bf16)f3.x; p1[5] = (bf16)f3.y; p1[6] = (bf16)f3.z; p1[7] = (bf16)f3.w;
            *(bf16x8*)&As[sr * LDA + seg] = p0;
            *(bf16x8*)&As[sr * LDA + seg + 8] = p1;
        }
        {
            const bf16x8* Bg = (const bf16x8*)(Bt + (long)(colBase + sr) * K + k0 + seg);
            *(bf16x8*)&Bs[sr * LDA + seg] = Bg[0];
            *(bf16x8*)&Bs[sr * LDA + seg + 8] = Bg[1];
        }
        __syncthreads();

        bf16x8 af[4], bfr[4];
#pragma unroll
        for (int mi = 0; mi < 4; mi++)
            af[mi] = *(const bf16x8*)&As[(m_base + mi * 16 + l16) * LDA + quad * 8];
#pragma unroll
        for (int ni = 0; ni < 4; ni++)
            bfr[ni] = *(const bf16x8*)&Bs[(n_base + ni * 16 + l16) * LDA + quad * 8];
#pragma unroll
        for (int mi = 0; mi < 4; mi++)
#pragma unroll
            for (int ni = 0; ni < 4; ni++)
                acc[mi][ni] = __builtin_amdgcn_mfma_f32_16x16x32_bf16(af[mi], bfr[ni], acc[mi][ni], 0, 0, 0);
        __syncthreads();
    }

    // epilogue: C/D layout col=lane&15, row=quad*4+reg  [m89-verified]; write bf16
#pragma unroll
    for (int mi = 0; mi < 4; mi++) {
#pragma unroll
        for (int r = 0; r < 4; r++) {
            const int grow = rowBase + m_base + mi * 16 + quad * 4 + r;
            if (grow < N) {
#pragma unroll
                for (int ni = 0; ni < 4; ni++) {
                    Fb[(long)grow * 256 + colBase + n_base + ni * 16 + l16] = (bf16)acc[mi][ni][r];
                }
            }
        }
    }
}

// ---------------- fp32 GEMM (layer-2 combined W2|rW2) ----------------
template <int BM, int BN, int BK, int TM, int TN>
__global__ void gemm_kernel(const float* __restrict__ A, const float* __restrict__ B,
                            float* __restrict__ C, int N, int K, int M) {
    constexpr int TX = BN / TN;
    constexpr int TY = BM / TM;
    constexpr int NT = TX * TY;
    __shared__ float As[BK][BM + 1];
    __shared__ float Bs[BK][BN + 1];

    const int tid = threadIdx.x;
    const int tx = tid % TX, ty = tid / TX;
    const int rowBase = blockIdx.y * BM;
    const int colBase = blockIdx.x * BN;

    float acc[TM][TN];
#pragma unroll
    for (int i = 0; i < TM; i++)
#pragma unroll
        for (int j = 0; j < TN; j++) acc[i][j] = 0.f;

    for (int k0 = 0; k0 < K; k0 += BK) {
        for (int idx = tid; idx < BM * BK; idx += NT) {
            int r = idx / BK, c = idx % BK;
            int gr = rowBase + r;
            As[c][r] = (gr < N) ? A[(long)gr * K + k0 + c] : 0.f;
        }
        for (int idx = tid; idx < BK * BN; idx += NT) {
            int r = idx / BN, c = idx % BN;
            Bs[r][c] = B[(long)(k0 + r) * M + colBase + c];
        }
        __syncthreads();
#pragma unroll
        for (int k = 0; k < BK; k++) {
            float a[TM], b[TN];
#pragma unroll
            for (int i = 0; i < TM; i++) a[i] = As[k][ty * TM + i];
#pragma unroll
            for (int j = 0; j < TN; j++) b[j] = Bs[k][tx * TN + j];
#pragma unroll
            for (int i = 0; i < TM; i++)
#pragma unroll
                for (int j = 0; j < TN; j++) acc[i][j] += a[i] * b[j];
        }
        __syncthreads();
    }
#pragma unroll
    for (int i = 0; i < TM; i++) {
        int gr = rowBase + ty * TM + i;
        if (gr < N) {
#pragma unroll
            for (int j = 0; j < TN; j++) {
                C[(long)gr * M + colBase + tx * TN + j] = acc[i][j];
            }
        }
    }
}

// ---------------- el/er from bf16 feat ----------------
template <int H, int D>
__global__ void el_er_kernel_bf16(const bf16* __restrict__ feat,
                                  const float* __restrict__ al, const float* __restrict__ ar,
                                  float* __restrict__ el, float* __restrict__ er, int N) {
    const int wid = (blockIdx.x * blockDim.x + threadIdx.x) >> 6;
    const int lane = threadIdx.x & 63;
    if (wid >= N * H) return;
    const int n = wid / H, h = wid % H;
    float vl = 0.f, vr = 0.f;
    if (lane < D) {
        float f = (float)feat[((long)n * H + h) * D + lane];
        vl = f * al[h * D + lane];
        vr = f * ar[h * D + lane];
    }
#pragma unroll
    for (int off = 32; off > 0; off >>= 1) {
        vl += __shfl_down(vl, off);
        vr += __shfl_down(vr, off);
    }
    if (lane == 0) { el[wid] = vl; er[wid] = vr; }
}

// el/er from fp32 feat with row stride (layer 2)
template <int H, int D>
__global__ void el_er_strided(const float* __restrict__ feat, int stride,
                              const float* __restrict__ al, const float* __restrict__ ar,
                              float* __restrict__ el, float* __restrict__ er, int N) {
    const int wid = (blockIdx.x * blockDim.x + threadIdx.x) >> 6;
    const int lane = threadIdx.x & 63;
    if (wid >= N * H) return;
    const int n = wid / H, h = wid % H;
    float vl = 0.f, vr = 0.f;
    if (lane < D) {
        float f = feat[(long)n * stride + h * D + lane];
        vl = f * al[h * D + lane];
        vr = f * ar[h * D + lane];
    }
#pragma unroll
    for (int off = 32; off > 0; off >>= 1) {
        vl += __shfl_down(vl, off);
        vr += __shfl_down(vr, off);
    }
    if (lane == 0) { el[wid] = vl; er[wid] = vr; }
}

// ---------------- CSR build ----------------

__global__ void count_deg_kernel(const int* __restrict__ dst, int* __restrict__ deg, int E) {
    const int e = blockIdx.x * blockDim.x + threadIdx.x;
    if (e >= E) return;
    atomicAdd(&deg[dst[e]], 1);
}

// 3-kernel scan: block-scan (256 thr x 4 items = 1024/block) -> scan block sums -> apply
__global__ void scan_block_kernel(const int* __restrict__ deg, int* __restrict__ scanned,
                                  int* __restrict__ block_sums, int N) {
    __shared__ int smem[256];
    const int tid = threadIdx.x;
    const int base = blockIdx.x * 1024 + tid * 4;
    int v[4];
#pragma unroll
    for (int i = 0; i < 4; i++) v[i] = (base + i < N) ? deg[base + i] : 0;
    const int tsum = v[0] + v[1] + v[2] + v[3];
    smem[tid] = tsum;
    __syncthreads();
    int acc = tsum;
    for (int off = 1; off < 256; off <<= 1) {
        const int t = (tid >= off) ? smem[tid - off] : 0;
        __syncthreads();
        acc += t;
        smem[tid] = acc;
        __syncthreads();
    }
    if (tid == 255) block_sums[blockIdx.x] = acc;
    int run = acc - tsum;  // exclusive within block
#pragma unroll
    for (int i = 0; i < 4; i++) {
        if (base + i < N) scanned[base + i] = run;
        run += v[i];
    }
}

// single wave: exclusive-scan block_sums in place (nb <= 64)
__global__ void scan_sums_kernel(int* __restrict__ block_sums, int nb) {
    const int tid = threadIdx.x;
    const int orig = (tid < nb) ? block_sums[tid] : 0;
    int v = orig;
#pragma unroll
    for (int off = 1; off < 64; off <<= 1) {
        const int t = __shfl_up(v, off);
        if (tid >= off) v += t;
    }
    if (tid < nb) block_sums[tid] = v - orig;
}

// row_ptr[i] = cursor[i] = scanned[i] + block_sums[i/1024]; row_ptr[N] = E
__global__ void apply_offsets_kernel(const int* __restrict__ scanned, const int* __restrict__ block_sums,
                                     int* __restrict__ row_ptr, int* __restrict__ cursor, int N, int E) {
    const int i = blockIdx.x * blockDim.x + threadIdx.x;
    if (i < N) {
        const int v = scanned[i] + block_sums[i >> 10];
        row_ptr[i] = v;
        cursor[i] = v;
    }
    if (i == 0) row_ptr[N] = E;
}

__global__ void scatter_kernel(const int* __restrict__ src, const int* __restrict__ dst,
                               int* __restrict__ cursor, int* __restrict__ csr_src, int E) {
    const int e = blockIdx.x * blockDim.x + threadIdx.x;
    if (e >= E) return;
    const int pos = atomicAdd(&cursor[dst[e]], 1);
    csr_src[pos] = src[e];
}

// ---------------- attention weights: one THREAD per (node, head) ----------------
template <int H>
__global__ void attn_weight_kernel(const int* __restrict__ row_ptr, const int* __restrict__ csr_src,
                                   const float* __restrict__ el, const float* __restrict__ er,
                                   float* __restrict__ attn, int N) {
    const int t = blockIdx.x * blockDim.x + threadIdx.x;
    if (t >= N * H) return;
    const int n = t / H, h = t % H;
    const float erd = er[n * H + h];
    const int p0 = row_ptr[n], p1 = row_ptr[n + 1];
    float m = -INFINITY;
    for (int p = p0; p < p1; ++p) {
        float e = el[csr_src[p] * H + h] + erd;
        e = (e >= 0.f) ? e : 0.2f * e;
        attn[p * H + h] = e;
        m = fmaxf(m, e);
    }
    float denom = 0.f;
    for (int p = p0; p < p1; ++p) {
        const float w = expf(attn[p * H + h] - m);
        attn[p * H + h] = w;
        denom += w;
    }
    const float inv = (denom > 0.f) ? 1.f / denom : 0.f;
    for (int p = p0; p < p1; ++p) attn[p * H + h] *= inv;
}

// ---------------- aggregate: one WAVE per node, 4-edge unroll for MLP ----------
template <int H, int D, bool ACT>
__global__ void gat_aggregate_wave(const int* __restrict__ row_ptr, const int* __restrict__ csr_src,
                                   const float* __restrict__ attn, const bf16* __restrict__ feat,
                                   const float* __restrict__ res, const float* __restrict__ bias,
                                   float* __restrict__ out, int N) {
    constexpr int C = H * D;       // 256
    constexpr int V = C / 4;       // 64 bf16x4 per node row
    const int wave = threadIdx.x >> 6;
    const int lane = threadIdx.x & 63;
    int n = blockIdx.x * (blockDim.x >> 6) + wave;
    if (n >= N) return;
    n = __builtin_amdgcn_readfirstlane(n);   // wave-uniform -> s_loads for row_ptr/csr_src
    const int h = (lane * 4) / D;
    const bf16x4* feat4 = (const bf16x4*)feat;

    float4 acc = {0.f, 0.f, 0.f, 0.f};
    int p = row_ptr[n];
    const int pend = row_ptr[n + 1];
    for (; p + 4 <= pend; p += 4) {
        const int s0 = csr_src[p + 0];
        const int s1 = csr_src[p + 1];
        const int s2 = csr_src[p + 2];
        const int s3 = csr_src[p + 3];
        const float w0 = attn[(p + 0) * H + h];
        const float w1 = attn[(p + 1) * H + h];
        const float w2 = attn[(p + 2) * H + h];
        const float w3 = attn[(p + 3) * H + h];
        const bf16x4 f0 = feat4[(long)s0 * V + lane];
        const bf16x4 f1 = feat4[(long)s1 * V + lane];
        const bf16x4 f2 = feat4[(long)s2 * V + lane];
        const bf16x4 f3 = feat4[(long)s3 * V + lane];
        acc.x += w0 * (float)f0[0] + w1 * (float)f1[0] + w2 * (float)f2[0] + w3 * (float)f3[0];
        acc.y += w0 * (float)f0[1] + w1 * (float)f1[1] + w2 * (float)f2[1] + w3 * (float)f3[1];
        acc.z += w0 * (float)f0[2] + w1 * (float)f1[2] + w2 * (float)f2[2] + w3 * (float)f3[2];
        acc.w += w0 * (float)f0[3] + w1 * (float)f1[3] + w2 * (float)f2[3] + w3 * (float)f3[3];
    }
    for (; p < pend; ++p) {
        const int s = csr_src[p];
        const float w = attn[p * H + h];
        const bf16x4 f = feat4[(long)s * V + lane];
        acc.x += w * (float)f[0];
        acc.y += w * (float)f[1];
        acc.z += w * (float)f[2];
        acc.w += w * (float)f[3];
    }
    const float4 r = ((const float4*)res)[(long)n * V + lane];
    const float4 bb = ((const float4*)bias)[lane];
    float v[4] = {acc.x + r.x + bb.x, acc.y + r.y + bb.y,
                  acc.z + r.z + bb.z, acc.w + r.w + bb.w};
    if (ACT) {
#pragma unroll
        for (int i = 0; i < 4; i++) {
            const float sp = (v[i] > 20.f) ? v[i] : log1pf(expf(v[i]));
            v[i] = v[i] * tanhf(sp);
        }
    }
    float4 o = {v[0], v[1], v[2], v[3]};
    ((float4*)out)[(long)n * V + lane] = o;
}

// ---------------- small-C aggregate (layer 2): thread per channel, strided -------
template <int H, int D, bool ACT, int NPB>
__global__ void gat_aggregate_small(const int* __restrict__ row_ptr, const int* __restrict__ csr_src,
                                    const float* __restrict__ attn,
                                    const float* __restrict__ feat, int fstride,
                                    const float* __restrict__ res, int rstride,
                                    const float* __restrict__ bias, float* __restrict__ out, int N) {
    constexpr int C = H * D;
    const int local = threadIdx.x % C;
    const int n = blockIdx.x * NPB + threadIdx.x / C;
    if (n >= N) return;
    const int h = local / D;
    float acc = 0.f;
    const int pend = row_ptr[n + 1];
    for (int p = row_ptr[n]; p < pend; ++p) {
        const int s = csr_src[p];
        acc += attn[p * H + h] * feat[(long)s * fstride + local];
    }
    float v = acc + res[(long)n * rstride + local] + bias[local];
    if (ACT) {
        const float sp = (v > 20.f) ? v : log1pf(expf(v));
        v = v * tanhf(sp);
    }
    out[(long)n * C + local] = v;
}

// ---------------- host orchestration ----------------

static inline int cdiv(long a, long b) { return (int)((a + b - 1) / b); }

extern "C" void kernel_launch(void* const* d_in, const int* in_sizes, int n_in,
                              void* d_out, int out_size, void* d_ws, size_t ws_size,
                              hipStream_t stream) {
    const float* x   = (const float*)d_in[0];
    const int*   src = (const int*)d_in[1];
    const int*   dst = (const int*)d_in[2];
    const float* W0  = (const float*)d_in[3];
    const float* al0 = (const float*)d_in[4];
    const float* ar0 = (const float*)d_in[5];
    const float* b0  = (const float*)d_in[6];
    const float* W1  = (const float*)d_in[7];
    const float* al1 = (const float*)d_in[8];
    const float* ar1 = (const float*)d_in[9];
    const float* b1  = (const float*)d_in[10];
    const float* W2  = (const float*)d_in[11];
    const float* al2 = (const float*)d_in[12];
    const float* ar2 = (const float*)d_in[13];
    const float* b2  = (const float*)d_in[14];
    const float* rW2 = (const float*)d_in[15];
    float* out = (float*)d_out;

    const int N = in_sizes[0] / 256;   // 50000
    const int E = in_sizes[1];         // 800000
    const int K = 256;

    // workspace layout
    bf16* Wt0    = (bf16*)d_ws;               // 256*256 bf16
    bf16* Wt1    = Wt0 + 65536;               // 256*256 bf16
    bf16* Fb     = Wt1 + 65536;               // N*256 bf16 feat
    float* Bc    = (float*)(Fb + (long)N * 256);  // 256*32 combined W2|rW2
    float* F2    = Bc + 256 * 32;             // N*32 (layer2 feat | res)
    float* Hb    = F2 + (long)N * 32;         // N*256 hidden (fp32)
    float* el    = Hb + (long)N * 256;        // N*4
    float* er    = el + (long)N * 4;          // N*4
    float* attn  = er + (long)N * 4;          // E*4
    int* deg     = (int*)(attn + (long)E * 4);// N
    int* scanned = deg + N;                   // N
    int* bsums   = scanned + N;               // 64
    int* row_ptr = bsums + 64;                // N+1
    int* cursor  = row_ptr + N + 1;           // N
    int* csr_src = cursor + N;                // E

    const int THREADS = 256;
    const int NB = cdiv(N, 1024);
    dim3 mfma_grid(2, cdiv(N, 128));
    dim3 gemm32_grid(1, cdiv(N, 64));

    // ---------- weight prep + CSR build (reused by all layers) ----------
    transpose_cast_kernel<<<cdiv(65536, THREADS), THREADS, 0, stream>>>(W0, Wt0, K, 256);
    transpose_cast_kernel<<<cdiv(65536, THREADS), THREADS, 0, stream>>>(W1, Wt1, K, 256);
    concat_w2_kernel<<<cdiv(256 * 32, THREADS), THREADS, 0, stream>>>(W2, rW2, Bc);
    hipMemsetAsync(deg, 0, (size_t)N * 4, stream);
    count_deg_kernel<<<cdiv(E, THREADS), THREADS, 0, stream>>>(dst, deg, E);
    scan_block_kernel<<<NB, 256, 0, stream>>>(deg, scanned, bsums, N);
    scan_sums_kernel<<<1, 64, 0, stream>>>(bsums, NB);
    apply_offsets_kernel<<<cdiv(N, THREADS), THREADS, 0, stream>>>(scanned, bsums, row_ptr, cursor, N, E);
    scatter_kernel<<<cdiv(E, THREADS), THREADS, 0, stream>>>(src, dst, cursor, csr_src, E);

    // ================= Layer 0 (H=4, D=64), input x, residual = x =================
    gemm_mfma_bf16<<<mfma_grid, 256, 0, stream>>>(x, Wt0, Fb, N);
    el_er_kernel_bf16<4, 64><<<cdiv((long)N * 4 * 64, THREADS), THREADS, 0, stream>>>(Fb, al0, ar0, el, er, N);
    attn_weight_kernel<4><<<cdiv((long)N * 4, THREADS), THREADS, 0, stream>>>(row_ptr, csr_src, el, er, attn, N);
    gat_aggregate_wave<4, 64, true><<<cdiv(N, 4), 256, 0, stream>>>(row_ptr, csr_src, attn, Fb, x, b0, Hb, N);

    // ================= Layer 1 (H=4, D=64), input Hb, residual = Hb ===============
    gemm_mfma_bf16<<<mfma_grid, 256, 0, stream>>>(Hb, Wt1, Fb, N);
    el_er_kernel_bf16<4, 64><<<cdiv((long)N * 4 * 64, THREADS), THREADS, 0, stream>>>(Fb, al1, ar1, el, er, N);
    attn_weight_kernel<4><<<cdiv((long)N * 4, THREADS), THREADS, 0, stream>>>(row_ptr, csr_src, el, er, attn, N);
    gat_aggregate_wave<4, 64, true><<<cdiv(N, 4), 256, 0, stream>>>(row_ptr, csr_src, attn, Fb, Hb, b1, Hb, N);

    // ================= Layer 2 (H=1, D=16): F2 = Hb @ [W2|rW2] =====================
    gemm_kernel<64, 32, 16, 4, 4><<<gemm32_grid, 128, 0, stream>>>(Hb, Bc, F2, N, K, 32);
    el_er_strided<1, 16><<<cdiv((long)N * 64, THREADS), THREADS, 0, stream>>>(F2, 32, al2, ar2, el, er, N);
    attn_weight_kernel<1><<<cdiv((long)N, THREADS), THREADS, 0, stream>>>(row_ptr, csr_src, el, er, attn, N);
    gat_aggregate_small<1, 16, false, 16><<<cdiv(N, 16), 256, 0, stream>>>(row_ptr, csr_src, attn,
                                                                           F2, 32, F2 + 16, 32, b2, out, N);
}

// Round 7
// 605.270 us; speedup vs baseline: 3.9749x; 1.0637x over previous
//
#include <hip/hip_runtime.h>
#include <cmath>
#include <type_traits>

typedef __bf16 bf16;
typedef __attribute__((ext_vector_type(8))) __bf16 bf16x8;
typedef __attribute__((ext_vector_type(4))) __bf16 bf16x4;
typedef __attribute__((ext_vector_type(4))) float f32x4;

// ---------------- weight prep: W[K,M] fp32 -> Wt[M,K] bf16 ----------------
__global__ void transpose_cast_kernel(const float* __restrict__ W, bf16* __restrict__ Wt,
                                      int K, int M) {
    const int idx = blockIdx.x * blockDim.x + threadIdx.x;
    if (idx >= K * M) return;
    const int k = idx / M, m = idx % M;
    Wt[m * K + k] = (bf16)W[idx];
}

// concat W2[256,16] | rW2[256,16] -> Bc[256,32]
__global__ void concat_w2_kernel(const float* __restrict__ W2, const float* __restrict__ rW2,
                                 float* __restrict__ Bc) {
    const int idx = blockIdx.x * blockDim.x + threadIdx.x;
    if (idx >= 256 * 32) return;
    const int k = idx / 32, m = idx % 32;
    Bc[idx] = (m < 16) ? W2[k * 16 + m] : rW2[k * 16 + (m - 16)];
}

// ---------------- MFMA GEMM: Fb[N,256](bf16) = A[N,256] @ B (Bt bf16) ----
// AT = float (converted in staging) or bf16 (direct copy).
template <typename AT>
__global__ __launch_bounds__(256) void gemm_mfma_bf16(const AT* __restrict__ A,
                                                      const bf16* __restrict__ Bt,
                                                      bf16* __restrict__ Fb, int N) {
    constexpr int K = 256, BM = 128, BK = 32;
    constexpr int LDA = BK + 8;
    __shared__ bf16 As[BM * LDA];
    __shared__ bf16 Bs[BM * LDA];

    const int tid = threadIdx.x;
    const int wave = tid >> 6, lane = tid & 63;
    const int quad = lane >> 4, l16 = lane & 15;
    const int rowBase = blockIdx.y * BM;
    const int colBase = blockIdx.x * BM;
    const int m_base = (wave >> 1) * 64, n_base = (wave & 1) * 64;

    f32x4 acc[4][4] = {};

    const int sr = tid >> 1;
    const int seg = (tid & 1) << 4;

    for (int k0 = 0; k0 < K; k0 += BK) {
        {
            const int gr = rowBase + sr;
            if constexpr (std::is_same<AT, float>::value) {
                float4 f0 = {0,0,0,0}, f1 = {0,0,0,0}, f2 = {0,0,0,0}, f3 = {0,0,0,0};
                if (gr < N) {
                    const float4* Ag = (const float4*)(A + (long)gr * K + k0 + seg);
                    f0 = Ag[0]; f1 = Ag[1]; f2 = Ag[2]; f3 = Ag[3];
                }
                bf16x8 p0, p1;
                p0[0] = (bf16)f0.x; p0[1] = (bf16)f0.y; p0[2] = (bf16)f0.z; p0[3] = (bf16)f0.w;
                p0[4] = (bf16)f1.x; p0[5] = (bf16)f1.y; p0[6] = (bf16)f1.z; p0[7] = (bf16)f1.w;
                p1[0] = (bf16)f2.x; p1[1] = (bf16)f2.y; p1[2] = (bf16)f2.z; p1[3] = (bf16)f2.w;
                p1[4] = (bf16)f3.x; p1[5] = (bf16)f3.y; p1[6] = (bf16)f3.z; p1[7] = (bf16)f3.w;
                *(bf16x8*)&As[sr * LDA + seg] = p0;
                *(bf16x8*)&As[sr * LDA + seg + 8] = p1;
            } else {
                bf16x8 p0 = {}, p1 = {};
                if (gr < N) {
                    const bf16x8* Ag = (const bf16x8*)(A + (long)gr * K + k0 + seg);
                    p0 = Ag[0]; p1 = Ag[1];
                }
                *(bf16x8*)&As[sr * LDA + seg] = p0;
                *(bf16x8*)&As[sr * LDA + seg + 8] = p1;
            }
        }
        {
            const bf16x8* Bg = (const bf16x8*)(Bt + (long)(colBase + sr) * K + k0 + seg);
            *(bf16x8*)&Bs[sr * LDA + seg] = Bg[0];
            *(bf16x8*)&Bs[sr * LDA + seg + 8] = Bg[1];
        }
        __syncthreads();

        bf16x8 af[4], bfr[4];
#pragma unroll
        for (int mi = 0; mi < 4; mi++)
            af[mi] = *(const bf16x8*)&As[(m_base + mi * 16 + l16) * LDA + quad * 8];
#pragma unroll
        for (int ni = 0; ni < 4; ni++)
            bfr[ni] = *(const bf16x8*)&Bs[(n_base + ni * 16 + l16) * LDA + quad * 8];
#pragma unroll
        for (int mi = 0; mi < 4; mi++)
#pragma unroll
            for (int ni = 0; ni < 4; ni++)
                acc[mi][ni] = __builtin_amdgcn_mfma_f32_16x16x32_bf16(af[mi], bfr[ni], acc[mi][ni], 0, 0, 0);
        __syncthreads();
    }

    // epilogue: C/D layout col=lane&15, row=quad*4+reg  [m89-verified]; write bf16
#pragma unroll
    for (int mi = 0; mi < 4; mi++) {
#pragma unroll
        for (int r = 0; r < 4; r++) {
            const int grow = rowBase + m_base + mi * 16 + quad * 4 + r;
            if (grow < N) {
#pragma unroll
                for (int ni = 0; ni < 4; ni++) {
                    Fb[(long)grow * 256 + colBase + n_base + ni * 16 + l16] = (bf16)acc[mi][ni][r];
                }
            }
        }
    }
}

// ---------------- fp32 GEMM with castable A (layer-2 combined W2|rW2) ----------------
template <int BM, int BN, int BK, int TM, int TN, typename AT>
__global__ void gemm_kernel(const AT* __restrict__ A, const float* __restrict__ B,
                            float* __restrict__ C, int N, int K, int M) {
    constexpr int TX = BN / TN;
    constexpr int TY = BM / TM;
    constexpr int NT = TX * TY;
    __shared__ float As[BK][BM + 1];
    __shared__ float Bs[BK][BN + 1];

    const int tid = threadIdx.x;
    const int tx = tid % TX, ty = tid / TX;
    const int rowBase = blockIdx.y * BM;
    const int colBase = blockIdx.x * BN;

    float acc[TM][TN];
#pragma unroll
    for (int i = 0; i < TM; i++)
#pragma unroll
        for (int j = 0; j < TN; j++) acc[i][j] = 0.f;

    for (int k0 = 0; k0 < K; k0 += BK) {
        for (int idx = tid; idx < BM * BK; idx += NT) {
            int r = idx / BK, c = idx % BK;
            int gr = rowBase + r;
            As[c][r] = (gr < N) ? (float)A[(long)gr * K + k0 + c] : 0.f;
        }
        for (int idx = tid; idx < BK * BN; idx += NT) {
            int r = idx / BN, c = idx % BN;
            Bs[r][c] = B[(long)(k0 + r) * M + colBase + c];
        }
        __syncthreads();
#pragma unroll
        for (int k = 0; k < BK; k++) {
            float a[TM], b[TN];
#pragma unroll
            for (int i = 0; i < TM; i++) a[i] = As[k][ty * TM + i];
#pragma unroll
            for (int j = 0; j < TN; j++) b[j] = Bs[k][tx * TN + j];
#pragma unroll
            for (int i = 0; i < TM; i++)
#pragma unroll
                for (int j = 0; j < TN; j++) acc[i][j] += a[i] * b[j];
        }
        __syncthreads();
    }
#pragma unroll
    for (int i = 0; i < TM; i++) {
        int gr = rowBase + ty * TM + i;
        if (gr < N) {
#pragma unroll
            for (int j = 0; j < TN; j++) {
                C[(long)gr * M + colBase + tx * TN + j] = acc[i][j];
            }
        }
    }
}

// ---------------- el/er: one WAVE per node, all 4 heads (C=256, D=64) -----------
// lane loads bf16x4 channels; al/ar are channel-contiguous; 16-lane groups per head.
__global__ void el_er_node_kernel(const bf16* __restrict__ feat,
                                  const float* __restrict__ al, const float* __restrict__ ar,
                                  float* __restrict__ el, float* __restrict__ er, int N) {
    const int wid = (blockIdx.x * blockDim.x + threadIdx.x) >> 6;
    const int lane = threadIdx.x & 63;
    if (wid >= N) return;
    const bf16x4 f = ((const bf16x4*)feat)[(long)wid * 64 + lane];
    const float4 a = ((const float4*)al)[lane];
    const float4 b = ((const float4*)ar)[lane];
    const float f0 = (float)f[0], f1 = (float)f[1], f2 = (float)f[2], f3 = (float)f[3];
    float vl = f0 * a.x + f1 * a.y + f2 * a.z + f3 * a.w;
    float vr = f0 * b.x + f1 * b.y + f2 * b.z + f3 * b.w;
#pragma unroll
    for (int off = 1; off < 16; off <<= 1) {
        vl += __shfl_xor(vl, off);
        vr += __shfl_xor(vr, off);
    }
    if ((lane & 15) == 0) {
        const int h = lane >> 4;
        el[wid * 4 + h] = vl;
        er[wid * 4 + h] = vr;
    }
}

// el/er from fp32 feat with row stride (layer 2)
template <int H, int D>
__global__ void el_er_strided(const float* __restrict__ feat, int stride,
                              const float* __restrict__ al, const float* __restrict__ ar,
                              float* __restrict__ el, float* __restrict__ er, int N) {
    const int wid = (blockIdx.x * blockDim.x + threadIdx.x) >> 6;
    const int lane = threadIdx.x & 63;
    if (wid >= N * H) return;
    const int n = wid / H, h = wid % H;
    float vl = 0.f, vr = 0.f;
    if (lane < D) {
        float f = feat[(long)n * stride + h * D + lane];
        vl = f * al[h * D + lane];
        vr = f * ar[h * D + lane];
    }
#pragma unroll
    for (int off = 32; off > 0; off >>= 1) {
        vl += __shfl_down(vl, off);
        vr += __shfl_down(vr, off);
    }
    if (lane == 0) { el[wid] = vl; er[wid] = vr; }
}

// ---------------- CSR build ----------------

__global__ void count_deg_kernel(const int* __restrict__ dst, int* __restrict__ deg, int E) {
    const int e = blockIdx.x * blockDim.x + threadIdx.x;
    if (e >= E) return;
    atomicAdd(&deg[dst[e]], 1);
}

__global__ void scan_block_kernel(const int* __restrict__ deg, int* __restrict__ scanned,
                                  int* __restrict__ block_sums, int N) {
    __shared__ int smem[256];
    const int tid = threadIdx.x;
    const int base = blockIdx.x * 1024 + tid * 4;
    int v[4];
#pragma unroll
    for (int i = 0; i < 4; i++) v[i] = (base + i < N) ? deg[base + i] : 0;
    const int tsum = v[0] + v[1] + v[2] + v[3];
    smem[tid] = tsum;
    __syncthreads();
    int acc = tsum;
    for (int off = 1; off < 256; off <<= 1) {
        const int t = (tid >= off) ? smem[tid - off] : 0;
        __syncthreads();
        acc += t;
        smem[tid] = acc;
        __syncthreads();
    }
    if (tid == 255) block_sums[blockIdx.x] = acc;
    int run = acc - tsum;
#pragma unroll
    for (int i = 0; i < 4; i++) {
        if (base + i < N) scanned[base + i] = run;
        run += v[i];
    }
}

__global__ void scan_sums_kernel(int* __restrict__ block_sums, int nb) {
    const int tid = threadIdx.x;
    const int orig = (tid < nb) ? block_sums[tid] : 0;
    int v = orig;
#pragma unroll
    for (int off = 1; off < 64; off <<= 1) {
        const int t = __shfl_up(v, off);
        if (tid >= off) v += t;
    }
    if (tid < nb) block_sums[tid] = v - orig;
}

__global__ void apply_offsets_kernel(const int* __restrict__ scanned, const int* __restrict__ block_sums,
                                     int* __restrict__ row_ptr, int* __restrict__ cursor, int N, int E) {
    const int i = blockIdx.x * blockDim.x + threadIdx.x;
    if (i < N) {
        const int v = scanned[i] + block_sums[i >> 10];
        row_ptr[i] = v;
        cursor[i] = v;
    }
    if (i == 0) row_ptr[N] = E;
}

__global__ void scatter_kernel(const int* __restrict__ src, const int* __restrict__ dst,
                               int* __restrict__ cursor, int* __restrict__ csr_src, int E) {
    const int e = blockIdx.x * blockDim.x + threadIdx.x;
    if (e >= E) return;
    const int pos = atomicAdd(&cursor[dst[e]], 1);
    csr_src[pos] = src[e];
}

// ---------------- attention weights, H=4: one THREAD per node, float4 heads ------
__device__ __forceinline__ float4 leaky4(float4 e) {
    e.x = (e.x >= 0.f) ? e.x : 0.2f * e.x;
    e.y = (e.y >= 0.f) ? e.y : 0.2f * e.y;
    e.z = (e.z >= 0.f) ? e.z : 0.2f * e.z;
    e.w = (e.w >= 0.f) ? e.w : 0.2f * e.w;
    return e;
}

__global__ void attn_weight4_kernel(const int* __restrict__ row_ptr, const int* __restrict__ csr_src,
                                    const float* __restrict__ el, const float* __restrict__ er,
                                    float* __restrict__ attn, int N) {
    const int n = blockIdx.x * blockDim.x + threadIdx.x;
    if (n >= N) return;
    const float4 erd = ((const float4*)er)[n];
    const int p0 = row_ptr[n], p1 = row_ptr[n + 1];
    const float4* el4 = (const float4*)el;
    float4* attn4 = (float4*)attn;

    float4 m = {-INFINITY, -INFINITY, -INFINITY, -INFINITY};
    for (int p = p0; p < p1; ++p) {
        const float4 es = el4[csr_src[p]];
        float4 e = leaky4(make_float4(es.x + erd.x, es.y + erd.y, es.z + erd.z, es.w + erd.w));
        attn4[p] = e;
        m.x = fmaxf(m.x, e.x); m.y = fmaxf(m.y, e.y);
        m.z = fmaxf(m.z, e.z); m.w = fmaxf(m.w, e.w);
    }
    float4 denom = {0.f, 0.f, 0.f, 0.f};
    for (int p = p0; p < p1; ++p) {
        float4 e = attn4[p];
        e.x = expf(e.x - m.x); e.y = expf(e.y - m.y);
        e.z = expf(e.z - m.z); e.w = expf(e.w - m.w);
        attn4[p] = e;
        denom.x += e.x; denom.y += e.y; denom.z += e.z; denom.w += e.w;
    }
    const float4 inv = {(denom.x > 0.f) ? 1.f / denom.x : 0.f,
                        (denom.y > 0.f) ? 1.f / denom.y : 0.f,
                        (denom.z > 0.f) ? 1.f / denom.z : 0.f,
                        (denom.w > 0.f) ? 1.f / denom.w : 0.f};
    for (int p = p0; p < p1; ++p) {
        float4 e = attn4[p];
        e.x *= inv.x; e.y *= inv.y; e.z *= inv.z; e.w *= inv.w;
        attn4[p] = e;
    }
}

// layer-2 (H=1) scalar version
template <int H>
__global__ void attn_weight_kernel(const int* __restrict__ row_ptr, const int* __restrict__ csr_src,
                                   const float* __restrict__ el, const float* __restrict__ er,
                                   float* __restrict__ attn, int N) {
    const int t = blockIdx.x * blockDim.x + threadIdx.x;
    if (t >= N * H) return;
    const int n = t / H, h = t % H;
    const float erd = er[n * H + h];
    const int p0 = row_ptr[n], p1 = row_ptr[n + 1];
    float m = -INFINITY;
    for (int p = p0; p < p1; ++p) {
        float e = el[csr_src[p] * H + h] + erd;
        e = (e >= 0.f) ? e : 0.2f * e;
        attn[p * H + h] = e;
        m = fmaxf(m, e);
    }
    float denom = 0.f;
    for (int p = p0; p < p1; ++p) {
        const float w = expf(attn[p * H + h] - m);
        attn[p * H + h] = w;
        denom += w;
    }
    const float inv = (denom > 0.f) ? 1.f / denom : 0.f;
    for (int p = p0; p < p1; ++p) attn[p * H + h] *= inv;
}

// ---------------- aggregate: one WAVE per node, 4-edge unroll, RT/OT templated ----
template <int H, int D, bool ACT, typename RT, typename OT>
__global__ void gat_aggregate_wave(const int* __restrict__ row_ptr, const int* __restrict__ csr_src,
                                   const float* __restrict__ attn, const bf16* __restrict__ feat,
                                   const RT* __restrict__ res, const float* __restrict__ bias,
                                   OT* __restrict__ out, int N) {
    constexpr int C = H * D;       // 256
    constexpr int V = C / 4;       // 64 x 4-channel groups
    const int wave = threadIdx.x >> 6;
    const int lane = threadIdx.x & 63;
    int n = blockIdx.x * (blockDim.x >> 6) + wave;
    if (n >= N) return;
    n = __builtin_amdgcn_readfirstlane(n);   // wave-uniform -> s_loads for row_ptr/csr_src
    const int h = (lane * 4) / D;
    const bf16x4* feat4 = (const bf16x4*)feat;

    float4 acc = {0.f, 0.f, 0.f, 0.f};
    int p = row_ptr[n];
    const int pend = row_ptr[n + 1];
    for (; p + 4 <= pend; p += 4) {
        const int s0 = csr_src[p + 0];
        const int s1 = csr_src[p + 1];
        const int s2 = csr_src[p + 2];
        const int s3 = csr_src[p + 3];
        const float w0 = attn[(p + 0) * H + h];
        const float w1 = attn[(p + 1) * H + h];
        const float w2 = attn[(p + 2) * H + h];
        const float w3 = attn[(p + 3) * H + h];
        const bf16x4 f0 = feat4[(long)s0 * V + lane];
        const bf16x4 f1 = feat4[(long)s1 * V + lane];
        const bf16x4 f2 = feat4[(long)s2 * V + lane];
        const bf16x4 f3 = feat4[(long)s3 * V + lane];
        acc.x += w0 * (float)f0[0] + w1 * (float)f1[0] + w2 * (float)f2[0] + w3 * (float)f3[0];
        acc.y += w0 * (float)f0[1] + w1 * (float)f1[1] + w2 * (float)f2[1] + w3 * (float)f3[1];
        acc.z += w0 * (float)f0[2] + w1 * (float)f1[2] + w2 * (float)f2[2] + w3 * (float)f3[2];
        acc.w += w0 * (float)f0[3] + w1 * (float)f1[3] + w2 * (float)f2[3] + w3 * (float)f3[3];
    }
    for (; p < pend; ++p) {
        const int s = csr_src[p];
        const float w = attn[p * H + h];
        const bf16x4 f = feat4[(long)s * V + lane];
        acc.x += w * (float)f[0];
        acc.y += w * (float)f[1];
        acc.z += w * (float)f[2];
        acc.w += w * (float)f[3];
    }
    float4 r;
    if constexpr (std::is_same<RT, float>::value) {
        r = ((const float4*)res)[(long)n * V + lane];
    } else {
        const bf16x4 rb = ((const bf16x4*)res)[(long)n * V + lane];
        r = make_float4((float)rb[0], (float)rb[1], (float)rb[2], (float)rb[3]);
    }
    const float4 bb = ((const float4*)bias)[lane];
    float v[4] = {acc.x + r.x + bb.x, acc.y + r.y + bb.y,
                  acc.z + r.z + bb.z, acc.w + r.w + bb.w};
    if (ACT) {
#pragma unroll
        for (int i = 0; i < 4; i++) {
            const float sp = (v[i] > 20.f) ? v[i] : log1pf(expf(v[i]));
            v[i] = v[i] * tanhf(sp);
        }
    }
    if constexpr (std::is_same<OT, float>::value) {
        float4 o = {v[0], v[1], v[2], v[3]};
        ((float4*)out)[(long)n * V + lane] = o;
    } else {
        bf16x4 o;
        o[0] = (bf16)v[0]; o[1] = (bf16)v[1]; o[2] = (bf16)v[2]; o[3] = (bf16)v[3];
        ((bf16x4*)out)[(long)n * V + lane] = o;
    }
}

// ---------------- small-C aggregate (layer 2): thread per channel, strided -------
template <int H, int D, bool ACT, int NPB>
__global__ void gat_aggregate_small(const int* __restrict__ row_ptr, const int* __restrict__ csr_src,
                                    const float* __restrict__ attn,
                                    const float* __restrict__ feat, int fstride,
                                    const float* __restrict__ res, int rstride,
                                    const float* __restrict__ bias, float* __restrict__ out, int N) {
    constexpr int C = H * D;
    const int local = threadIdx.x % C;
    const int n = blockIdx.x * NPB + threadIdx.x / C;
    if (n >= N) return;
    const int h = local / D;
    float acc = 0.f;
    const int pend = row_ptr[n + 1];
    for (int p = row_ptr[n]; p < pend; ++p) {
        const int s = csr_src[p];
        acc += attn[p * H + h] * feat[(long)s * fstride + local];
    }
    float v = acc + res[(long)n * rstride + local] + bias[local];
    if (ACT) {
        const float sp = (v > 20.f) ? v : log1pf(expf(v));
        v = v * tanhf(sp);
    }
    out[(long)n * C + local] = v;
}

// ---------------- host orchestration ----------------

static inline int cdiv(long a, long b) { return (int)((a + b - 1) / b); }

extern "C" void kernel_launch(void* const* d_in, const int* in_sizes, int n_in,
                              void* d_out, int out_size, void* d_ws, size_t ws_size,
                              hipStream_t stream) {
    const float* x   = (const float*)d_in[0];
    const int*   src = (const int*)d_in[1];
    const int*   dst = (const int*)d_in[2];
    const float* W0  = (const float*)d_in[3];
    const float* al0 = (const float*)d_in[4];
    const float* ar0 = (const float*)d_in[5];
    const float* b0  = (const float*)d_in[6];
    const float* W1  = (const float*)d_in[7];
    const float* al1 = (const float*)d_in[8];
    const float* ar1 = (const float*)d_in[9];
    const float* b1  = (const float*)d_in[10];
    const float* W2  = (const float*)d_in[11];
    const float* al2 = (const float*)d_in[12];
    const float* ar2 = (const float*)d_in[13];
    const float* b2  = (const float*)d_in[14];
    const float* rW2 = (const float*)d_in[15];
    float* out = (float*)d_out;

    const int N = in_sizes[0] / 256;   // 50000
    const int E = in_sizes[1];         // 800000
    const int K = 256;

    // workspace layout (all segment starts 16B-aligned)
    bf16* Wt0    = (bf16*)d_ws;               // 256*256 bf16
    bf16* Wt1    = Wt0 + 65536;               // 256*256 bf16
    bf16* Fb     = Wt1 + 65536;               // N*256 bf16 feat
    bf16* Hb     = Fb + (long)N * 256;        // N*256 bf16 hidden
    float* Bc    = (float*)(Hb + (long)N * 256);  // 256*32 combined W2|rW2
    float* F2    = Bc + 256 * 32;             // N*32 (layer2 feat | res)
    float* el    = F2 + (long)N * 32;         // N*4
    float* er    = el + (long)N * 4;          // N*4
    float* attn  = er + (long)N * 4;          // E*4
    int* deg     = (int*)(attn + (long)E * 4);// N
    int* scanned = deg + N;                   // N
    int* bsums   = scanned + N;               // 64
    int* row_ptr = bsums + 64;                // N+1
    int* cursor  = row_ptr + N + 1;           // N
    int* csr_src = cursor + N;                // E

    const int THREADS = 256;
    const int NB = cdiv(N, 1024);
    dim3 mfma_grid(2, cdiv(N, 128));
    dim3 gemm32_grid(1, cdiv(N, 64));

    // ---------- weight prep + CSR build (reused by all layers) ----------
    transpose_cast_kernel<<<cdiv(65536, THREADS), THREADS, 0, stream>>>(W0, Wt0, K, 256);
    transpose_cast_kernel<<<cdiv(65536, THREADS), THREADS, 0, stream>>>(W1, Wt1, K, 256);
    concat_w2_kernel<<<cdiv(256 * 32, THREADS), THREADS, 0, stream>>>(W2, rW2, Bc);
    hipMemsetAsync(deg, 0, (size_t)N * 4, stream);
    count_deg_kernel<<<cdiv(E, THREADS), THREADS, 0, stream>>>(dst, deg, E);
    scan_block_kernel<<<NB, 256, 0, stream>>>(deg, scanned, bsums, N);
    scan_sums_kernel<<<1, 64, 0, stream>>>(bsums, NB);
    apply_offsets_kernel<<<cdiv(N, THREADS), THREADS, 0, stream>>>(scanned, bsums, row_ptr, cursor, N, E);
    scatter_kernel<<<cdiv(E, THREADS), THREADS, 0, stream>>>(src, dst, cursor, csr_src, E);

    // ================= Layer 0 (H=4, D=64), input x (fp32), out Hb (bf16) =========
    gemm_mfma_bf16<float><<<mfma_grid, 256, 0, stream>>>(x, Wt0, Fb, N);
    el_er_node_kernel<<<cdiv(N, 4), 256, 0, stream>>>(Fb, al0, ar0, el, er, N);
    attn_weight4_kernel<<<cdiv(N, THREADS), THREADS, 0, stream>>>(row_ptr, csr_src, el, er, attn, N);
    gat_aggregate_wave<4, 64, true, float, bf16><<<cdiv(N, 4), 256, 0, stream>>>(
        row_ptr, csr_src, attn, Fb, x, b0, Hb, N);

    // ================= Layer 1 (H=4, D=64), input Hb (bf16), in-place =============
    gemm_mfma_bf16<bf16><<<mfma_grid, 256, 0, stream>>>(Hb, Wt1, Fb, N);
    el_er_node_kernel<<<cdiv(N, 4), 256, 0, stream>>>(Fb, al1, ar1, el, er, N);
    attn_weight4_kernel<<<cdiv(N, THREADS), THREADS, 0, stream>>>(row_ptr, csr_src, el, er, attn, N);
    gat_aggregate_wave<4, 64, true, bf16, bf16><<<cdiv(N, 4), 256, 0, stream>>>(
        row_ptr, csr_src, attn, Fb, Hb, b1, Hb, N);

    // ================= Layer 2 (H=1, D=16): F2 = Hb @ [W2|rW2] =====================
    gemm_kernel<64, 32, 16, 4, 4, bf16><<<gemm32_grid, 128, 0, stream>>>(Hb, Bc, F2, N, K, 32);
    el_er_strided<1, 16><<<cdiv((long)N * 64, THREADS), THREADS, 0, stream>>>(F2, 32, al2, ar2, el, er, N);
    attn_weight_kernel<1><<<cdiv((long)N, THREADS), THREADS, 0, stream>>>(row_ptr, csr_src, el, er, attn, N);
    gat_aggregate_small<1, 16, false, 16><<<cdiv(N, 16), 256, 0, stream>>>(row_ptr, csr_src, attn,
                                                                           F2, 32, F2 + 16, 32, b2, out, N);
}

// Round 8
// 532.925 us; speedup vs baseline: 4.5145x; 1.1357x over previous
//
#include <hip/hip_runtime.h>
#include <cmath>
#include <type_traits>

typedef __bf16 bf16;
typedef __attribute__((ext_vector_type(8))) __bf16 bf16x8;
typedef __attribute__((ext_vector_type(4))) __bf16 bf16x4;
typedef __attribute__((ext_vector_type(4))) float f32x4;

__device__ __forceinline__ unsigned f2s(float x) {
    unsigned u = __float_as_uint(x);
    return (u & 0x80000000u) ? ~u : (u | 0x80000000u);
}
__device__ __forceinline__ float s2f(unsigned s) {
    return (s & 0x80000000u) ? __uint_as_float(s & 0x7FFFFFFFu)
                             : __uint_as_float(~s);
}

// ---------------- weight prep: W[K,M] fp32 -> Wt[M,K] bf16 ----------------
__global__ void transpose_cast_kernel(const float* __restrict__ W, bf16* __restrict__ Wt,
                                      int K, int M) {
    const int idx = blockIdx.x * blockDim.x + threadIdx.x;
    if (idx >= K * M) return;
    const int k = idx / M, m = idx % M;
    Wt[m * K + k] = (bf16)W[idx];
}

// concat+transpose: Bct[32,256] bf16 from W2[256,16] | rW2[256,16]
__global__ void concat_w2t_kernel(const float* __restrict__ W2, const float* __restrict__ rW2,
                                  bf16* __restrict__ Bct) {
    const int idx = blockIdx.x * blockDim.x + threadIdx.x;
    if (idx >= 32 * 256) return;
    const int m = idx / 256, k = idx % 256;
    const float v = (m < 16) ? W2[k * 16 + m] : rW2[k * 16 + (m - 16)];
    Bct[idx] = (bf16)v;
}

// ---------------- MFMA GEMM: Fb[N,256](bf16) = A[N,256] @ B (Bt bf16) ----
template <typename AT>
__global__ __launch_bounds__(256) void gemm_mfma_bf16(const AT* __restrict__ A,
                                                      const bf16* __restrict__ Bt,
                                                      bf16* __restrict__ Fb, int N) {
    constexpr int K = 256, BM = 128, BK = 32;
    constexpr int LDA = BK + 8;
    __shared__ bf16 As[BM * LDA];
    __shared__ bf16 Bs[BM * LDA];

    const int tid = threadIdx.x;
    const int wave = tid >> 6, lane = tid & 63;
    const int quad = lane >> 4, l16 = lane & 15;
    const int rowBase = blockIdx.y * BM;
    const int colBase = blockIdx.x * BM;
    const int m_base = (wave >> 1) * 64, n_base = (wave & 1) * 64;

    f32x4 acc[4][4] = {};

    const int sr = tid >> 1;
    const int seg = (tid & 1) << 4;

    for (int k0 = 0; k0 < K; k0 += BK) {
        {
            const int gr = rowBase + sr;
            if constexpr (std::is_same<AT, float>::value) {
                float4 f0 = {0,0,0,0}, f1 = {0,0,0,0}, f2 = {0,0,0,0}, f3 = {0,0,0,0};
                if (gr < N) {
                    const float4* Ag = (const float4*)(A + (long)gr * K + k0 + seg);
                    f0 = Ag[0]; f1 = Ag[1]; f2 = Ag[2]; f3 = Ag[3];
                }
                bf16x8 p0, p1;
                p0[0] = (bf16)f0.x; p0[1] = (bf16)f0.y; p0[2] = (bf16)f0.z; p0[3] = (bf16)f0.w;
                p0[4] = (bf16)f1.x; p0[5] = (bf16)f1.y; p0[6] = (bf16)f1.z; p0[7] = (bf16)f1.w;
                p1[0] = (bf16)f2.x; p1[1] = (bf16)f2.y; p1[2] = (bf16)f2.z; p1[3] = (bf16)f2.w;
                p1[4] = (bf16)f3.x; p1[5] = (bf16)f3.y; p1[6] = (bf16)f3.z; p1[7] = (bf16)f3.w;
                *(bf16x8*)&As[sr * LDA + seg] = p0;
                *(bf16x8*)&As[sr * LDA + seg + 8] = p1;
            } else {
                bf16x8 p0 = {}, p1 = {};
                if (gr < N) {
                    const bf16x8* Ag = (const bf16x8*)(A + (long)gr * K + k0 + seg);
                    p0 = Ag[0]; p1 = Ag[1];
                }
                *(bf16x8*)&As[sr * LDA + seg] = p0;
                *(bf16x8*)&As[sr * LDA + seg + 8] = p1;
            }
        }
        {
            const bf16x8* Bg = (const bf16x8*)(Bt + (long)(colBase + sr) * K + k0 + seg);
            *(bf16x8*)&Bs[sr * LDA + seg] = Bg[0];
            *(bf16x8*)&Bs[sr * LDA + seg + 8] = Bg[1];
        }
        __syncthreads();

        bf16x8 af[4], bfr[4];
#pragma unroll
        for (int mi = 0; mi < 4; mi++)
            af[mi] = *(const bf16x8*)&As[(m_base + mi * 16 + l16) * LDA + quad * 8];
#pragma unroll
        for (int ni = 0; ni < 4; ni++)
            bfr[ni] = *(const bf16x8*)&Bs[(n_base + ni * 16 + l16) * LDA + quad * 8];
#pragma unroll
        for (int mi = 0; mi < 4; mi++)
#pragma unroll
            for (int ni = 0; ni < 4; ni++)
                acc[mi][ni] = __builtin_amdgcn_mfma_f32_16x16x32_bf16(af[mi], bfr[ni], acc[mi][ni], 0, 0, 0);
        __syncthreads();
    }

    // epilogue: C/D layout col=lane&15, row=quad*4+reg  [m89-verified]; write bf16
#pragma unroll
    for (int mi = 0; mi < 4; mi++) {
#pragma unroll
        for (int r = 0; r < 4; r++) {
            const int grow = rowBase + m_base + mi * 16 + quad * 4 + r;
            if (grow < N) {
#pragma unroll
                for (int ni = 0; ni < 4; ni++) {
                    Fb[(long)grow * 256 + colBase + n_base + ni * 16 + l16] = (bf16)acc[mi][ni][r];
                }
            }
        }
    }
}

// ---------------- MFMA GEMM, narrow: C[N,32](fp32) = A[N,256](bf16) @ Bct^T --------
// BM=128, BN=32. 4 waves: wave computes 64x16 via 4x1 grid of 16x16x32 MFMAs.
__global__ __launch_bounds__(256) void gemm_mfma_n32(const bf16* __restrict__ A,
                                                     const bf16* __restrict__ Bt,
                                                     float* __restrict__ C, int N) {
    constexpr int K = 256, BM = 128, BK = 32;
    constexpr int LDA = BK + 8;
    __shared__ bf16 As[BM * LDA];
    __shared__ bf16 Bs[32 * LDA];

    const int tid = threadIdx.x;
    const int wave = tid >> 6, lane = tid & 63;
    const int quad = lane >> 4, l16 = lane & 15;
    const int rowBase = blockIdx.x * BM;
    const int m_base = (wave >> 1) * 64, n_base = (wave & 1) * 16;

    f32x4 acc[4] = {};

    const int sr = tid >> 1;
    const int seg = (tid & 1) << 4;

    for (int k0 = 0; k0 < K; k0 += BK) {
        {
            const int gr = rowBase + sr;
            bf16x8 p0 = {}, p1 = {};
            if (gr < N) {
                const bf16x8* Ag = (const bf16x8*)(A + (long)gr * K + k0 + seg);
                p0 = Ag[0]; p1 = Ag[1];
            }
            *(bf16x8*)&As[sr * LDA + seg] = p0;
            *(bf16x8*)&As[sr * LDA + seg + 8] = p1;
        }
        if (tid < 64) {
            const int br = tid >> 1;
            const bf16x8* Bg = (const bf16x8*)(Bt + br * K + k0 + seg);
            *(bf16x8*)&Bs[br * LDA + seg] = Bg[0];
            *(bf16x8*)&Bs[br * LDA + seg + 8] = Bg[1];
        }
        __syncthreads();

        const bf16x8 bfr = *(const bf16x8*)&Bs[(n_base + l16) * LDA + quad * 8];
#pragma unroll
        for (int mi = 0; mi < 4; mi++) {
            const bf16x8 af = *(const bf16x8*)&As[(m_base + mi * 16 + l16) * LDA + quad * 8];
            acc[mi] = __builtin_amdgcn_mfma_f32_16x16x32_bf16(af, bfr, acc[mi], 0, 0, 0);
        }
        __syncthreads();
    }

#pragma unroll
    for (int mi = 0; mi < 4; mi++) {
#pragma unroll
        for (int r = 0; r < 4; r++) {
            const int grow = rowBase + m_base + mi * 16 + quad * 4 + r;
            if (grow < N) C[(long)grow * 32 + n_base + l16] = acc[mi][r];
        }
    }
}

// ---------------- el/er: one WAVE per node, all 4 heads (C=256, D=64) -----------
__global__ void el_er_node_kernel(const bf16* __restrict__ feat,
                                  const float* __restrict__ al, const float* __restrict__ ar,
                                  float* __restrict__ el, float* __restrict__ er, int N) {
    const int wid = (blockIdx.x * blockDim.x + threadIdx.x) >> 6;
    const int lane = threadIdx.x & 63;
    if (wid >= N) return;
    const bf16x4 f = ((const bf16x4*)feat)[(long)wid * 64 + lane];
    const float4 a = ((const float4*)al)[lane];
    const float4 b = ((const float4*)ar)[lane];
    const float f0 = (float)f[0], f1 = (float)f[1], f2 = (float)f[2], f3 = (float)f[3];
    float vl = f0 * a.x + f1 * a.y + f2 * a.z + f3 * a.w;
    float vr = f0 * b.x + f1 * b.y + f2 * b.z + f3 * b.w;
#pragma unroll
    for (int off = 1; off < 16; off <<= 1) {
        vl += __shfl_xor(vl, off);
        vr += __shfl_xor(vr, off);
    }
    if ((lane & 15) == 0) {
        const int h = lane >> 4;
        el[wid * 4 + h] = vl;
        er[wid * 4 + h] = vr;
    }
}

// el/er from fp32 feat with row stride (layer 2)
template <int H, int D>
__global__ void el_er_strided(const float* __restrict__ feat, int stride,
                              const float* __restrict__ al, const float* __restrict__ ar,
                              float* __restrict__ el, float* __restrict__ er, int N) {
    const int wid = (blockIdx.x * blockDim.x + threadIdx.x) >> 6;
    const int lane = threadIdx.x & 63;
    if (wid >= N * H) return;
    const int n = wid / H, h = wid % H;
    float vl = 0.f, vr = 0.f;
    if (lane < D) {
        float f = feat[(long)n * stride + h * D + lane];
        vl = f * al[h * D + lane];
        vr = f * ar[h * D + lane];
    }
#pragma unroll
    for (int off = 32; off > 0; off >>= 1) {
        vl += __shfl_down(vl, off);
        vr += __shfl_down(vr, off);
    }
    if (lane == 0) { el[wid] = vl; er[wid] = vr; }
}

// ---------------- global max of el (as 4 float-lanes) ----------------
__global__ void init_elmax_kernel(unsigned* __restrict__ elmax_u) {
    if (threadIdx.x < 4) elmax_u[threadIdx.x] = f2s(-INFINITY);
}

__global__ void elmax4_kernel(const float4* __restrict__ el4, unsigned* __restrict__ elmax_u, int n4) {
    __shared__ float4 sm[256];
    float4 m = {-INFINITY, -INFINITY, -INFINITY, -INFINITY};
    for (int i = blockIdx.x * blockDim.x + threadIdx.x; i < n4; i += gridDim.x * blockDim.x) {
        const float4 v = el4[i];
        m.x = fmaxf(m.x, v.x); m.y = fmaxf(m.y, v.y);
        m.z = fmaxf(m.z, v.z); m.w = fmaxf(m.w, v.w);
    }
    sm[threadIdx.x] = m;
    __syncthreads();
    for (int off = 128; off > 0; off >>= 1) {
        if (threadIdx.x < off) {
            float4 o = sm[threadIdx.x + off];
            float4 c = sm[threadIdx.x];
            c.x = fmaxf(c.x, o.x); c.y = fmaxf(c.y, o.y);
            c.z = fmaxf(c.z, o.z); c.w = fmaxf(c.w, o.w);
            sm[threadIdx.x] = c;
        }
        __syncthreads();
    }
    if (threadIdx.x == 0) {
        const float4 r = sm[0];
        atomicMax(&elmax_u[0], f2s(r.x));
        atomicMax(&elmax_u[1], f2s(r.y));
        atomicMax(&elmax_u[2], f2s(r.z));
        atomicMax(&elmax_u[3], f2s(r.w));
    }
}

// ---------------- CSR build ----------------

__global__ void count_deg_kernel(const int* __restrict__ dst, int* __restrict__ deg, int E) {
    const int e = blockIdx.x * blockDim.x + threadIdx.x;
    if (e >= E) return;
    atomicAdd(&deg[dst[e]], 1);
}

__global__ void scan_block_kernel(const int* __restrict__ deg, int* __restrict__ scanned,
                                  int* __restrict__ block_sums, int N) {
    __shared__ int smem[256];
    const int tid = threadIdx.x;
    const int base = blockIdx.x * 1024 + tid * 4;
    int v[4];
#pragma unroll
    for (int i = 0; i < 4; i++) v[i] = (base + i < N) ? deg[base + i] : 0;
    const int tsum = v[0] + v[1] + v[2] + v[3];
    smem[tid] = tsum;
    __syncthreads();
    int acc = tsum;
    for (int off = 1; off < 256; off <<= 1) {
        const int t = (tid >= off) ? smem[tid - off] : 0;
        __syncthreads();
        acc += t;
        smem[tid] = acc;
        __syncthreads();
    }
    if (tid == 255) block_sums[blockIdx.x] = acc;
    int run = acc - tsum;
#pragma unroll
    for (int i = 0; i < 4; i++) {
        if (base + i < N) scanned[base + i] = run;
        run += v[i];
    }
}

__global__ void scan_sums_kernel(int* __restrict__ block_sums, int nb) {
    const int tid = threadIdx.x;
    const int orig = (tid < nb) ? block_sums[tid] : 0;
    int v = orig;
#pragma unroll
    for (int off = 1; off < 64; off <<= 1) {
        const int t = __shfl_up(v, off);
        if (tid >= off) v += t;
    }
    if (tid < nb) block_sums[tid] = v - orig;
}

__global__ void apply_offsets_kernel(const int* __restrict__ scanned, const int* __restrict__ block_sums,
                                     int* __restrict__ row_ptr, int* __restrict__ cursor, int N, int E) {
    const int i = blockIdx.x * blockDim.x + threadIdx.x;
    if (i < N) {
        const int v = scanned[i] + block_sums[i >> 10];
        row_ptr[i] = v;
        cursor[i] = v;
    }
    if (i == 0) row_ptr[N] = E;
}

__global__ void scatter_kernel(const int* __restrict__ src, const int* __restrict__ dst,
                               int* __restrict__ cursor, int* __restrict__ csr_src, int E) {
    const int e = blockIdx.x * blockDim.x + threadIdx.x;
    if (e >= E) return;
    const int pos = atomicAdd(&cursor[dst[e]], 1);
    csr_src[pos] = src[e];
}

// ---------------- attention weights: ONE pass, upper-bound shift ------------------
// shift = leaky(el_max + er[d]) >= e for all incoming edges (leaky monotonic),
// so exp(e-shift) <= 1 (no overflow); softmax ratio identical. Stores unnormalized
// w and inv_denom; aggregates apply the normalization.
__device__ __forceinline__ float4 leaky4(float4 e) {
    e.x = (e.x >= 0.f) ? e.x : 0.2f * e.x;
    e.y = (e.y >= 0.f) ? e.y : 0.2f * e.y;
    e.z = (e.z >= 0.f) ? e.z : 0.2f * e.z;
    e.w = (e.w >= 0.f) ? e.w : 0.2f * e.w;
    return e;
}

__global__ void attn_weight4_onepass(const int* __restrict__ row_ptr, const int* __restrict__ csr_src,
                                     const float* __restrict__ el, const float* __restrict__ er,
                                     const unsigned* __restrict__ elmax_u,
                                     float* __restrict__ attn, float* __restrict__ inv_d, int N) {
    const int n = blockIdx.x * blockDim.x + threadIdx.x;
    if (n >= N) return;
    const float4 erd = ((const float4*)er)[n];
    const float4 mx = {s2f(elmax_u[0]), s2f(elmax_u[1]), s2f(elmax_u[2]), s2f(elmax_u[3])};
    const float4 shift = leaky4(make_float4(mx.x + erd.x, mx.y + erd.y, mx.z + erd.z, mx.w + erd.w));
    const int p0 = row_ptr[n], p1 = row_ptr[n + 1];
    const float4* el4 = (const float4*)el;
    float4* attn4 = (float4*)attn;

    float4 denom = {0.f, 0.f, 0.f, 0.f};
    for (int p = p0; p < p1; ++p) {
        const float4 es = el4[csr_src[p]];
        float4 e = leaky4(make_float4(es.x + erd.x, es.y + erd.y, es.z + erd.z, es.w + erd.w));
        e.x = expf(e.x - shift.x); e.y = expf(e.y - shift.y);
        e.z = expf(e.z - shift.z); e.w = expf(e.w - shift.w);
        attn4[p] = e;
        denom.x += e.x; denom.y += e.y; denom.z += e.z; denom.w += e.w;
    }
    float4 inv = {(denom.x > 0.f) ? 1.f / denom.x : 0.f,
                  (denom.y > 0.f) ? 1.f / denom.y : 0.f,
                  (denom.z > 0.f) ? 1.f / denom.z : 0.f,
                  (denom.w > 0.f) ? 1.f / denom.w : 0.f};
    ((float4*)inv_d)[n] = inv;
}

__global__ void attn_weight1_onepass(const int* __restrict__ row_ptr, const int* __restrict__ csr_src,
                                     const float* __restrict__ el, const float* __restrict__ er,
                                     const unsigned* __restrict__ elmax_u,
                                     float* __restrict__ attn, float* __restrict__ inv_d, int N) {
    const int n = blockIdx.x * blockDim.x + threadIdx.x;
    if (n >= N) return;
    const float mx = fmaxf(fmaxf(s2f(elmax_u[0]), s2f(elmax_u[1])),
                           fmaxf(s2f(elmax_u[2]), s2f(elmax_u[3])));
    const float erd = er[n];
    float sh = mx + erd;
    sh = (sh >= 0.f) ? sh : 0.2f * sh;
    const int p0 = row_ptr[n], p1 = row_ptr[n + 1];
    float denom = 0.f;
    for (int p = p0; p < p1; ++p) {
        float e = el[csr_src[p]] + erd;
        e = (e >= 0.f) ? e : 0.2f * e;
        const float w = expf(e - sh);
        attn[p] = w;
        denom += w;
    }
    inv_d[n] = (denom > 0.f) ? 1.f / denom : 0.f;
}

// ---------------- aggregate: one WAVE per node, 4-edge unroll, applies inv_denom --
template <int H, int D, bool ACT, typename RT, typename OT>
__global__ void gat_aggregate_wave(const int* __restrict__ row_ptr, const int* __restrict__ csr_src,
                                   const float* __restrict__ attn, const float* __restrict__ inv_d,
                                   const bf16* __restrict__ feat,
                                   const RT* __restrict__ res, const float* __restrict__ bias,
                                   OT* __restrict__ out, int N) {
    constexpr int C = H * D;       // 256
    constexpr int V = C / 4;       // 64 x 4-channel groups
    const int wave = threadIdx.x >> 6;
    const int lane = threadIdx.x & 63;
    int n = blockIdx.x * (blockDim.x >> 6) + wave;
    if (n >= N) return;
    n = __builtin_amdgcn_readfirstlane(n);
    const int h = (lane * 4) / D;
    const bf16x4* feat4 = (const bf16x4*)feat;

    float4 acc = {0.f, 0.f, 0.f, 0.f};
    int p = row_ptr[n];
    const int pend = row_ptr[n + 1];
    for (; p + 4 <= pend; p += 4) {
        const int s0 = csr_src[p + 0];
        const int s1 = csr_src[p + 1];
        const int s2 = csr_src[p + 2];
        const int s3 = csr_src[p + 3];
        const float w0 = attn[(p + 0) * H + h];
        const float w1 = attn[(p + 1) * H + h];
        const float w2 = attn[(p + 2) * H + h];
        const float w3 = attn[(p + 3) * H + h];
        const bf16x4 f0 = feat4[(long)s0 * V + lane];
        const bf16x4 f1 = feat4[(long)s1 * V + lane];
        const bf16x4 f2 = feat4[(long)s2 * V + lane];
        const bf16x4 f3 = feat4[(long)s3 * V + lane];
        acc.x += w0 * (float)f0[0] + w1 * (float)f1[0] + w2 * (float)f2[0] + w3 * (float)f3[0];
        acc.y += w0 * (float)f0[1] + w1 * (float)f1[1] + w2 * (float)f2[1] + w3 * (float)f3[1];
        acc.z += w0 * (float)f0[2] + w1 * (float)f1[2] + w2 * (float)f2[2] + w3 * (float)f3[2];
        acc.w += w0 * (float)f0[3] + w1 * (float)f1[3] + w2 * (float)f2[3] + w3 * (float)f3[3];
    }
    for (; p < pend; ++p) {
        const int s = csr_src[p];
        const float w = attn[p * H + h];
        const bf16x4 f = feat4[(long)s * V + lane];
        acc.x += w * (float)f[0];
        acc.y += w * (float)f[1];
        acc.z += w * (float)f[2];
        acc.w += w * (float)f[3];
    }
    const float inv = inv_d[n * H + h];
    acc.x *= inv; acc.y *= inv; acc.z *= inv; acc.w *= inv;

    float4 r;
    if constexpr (std::is_same<RT, float>::value) {
        r = ((const float4*)res)[(long)n * V + lane];
    } else {
        const bf16x4 rb = ((const bf16x4*)res)[(long)n * V + lane];
        r = make_float4((float)rb[0], (float)rb[1], (float)rb[2], (float)rb[3]);
    }
    const float4 bb = ((const float4*)bias)[lane];
    float v[4] = {acc.x + r.x + bb.x, acc.y + r.y + bb.y,
                  acc.z + r.z + bb.z, acc.w + r.w + bb.w};
    if (ACT) {
#pragma unroll
        for (int i = 0; i < 4; i++) {
            const float sp = (v[i] > 20.f) ? v[i] : log1pf(expf(v[i]));
            v[i] = v[i] * tanhf(sp);
        }
    }
    if constexpr (std::is_same<OT, float>::value) {
        float4 o = {v[0], v[1], v[2], v[3]};
        ((float4*)out)[(long)n * V + lane] = o;
    } else {
        bf16x4 o;
        o[0] = (bf16)v[0]; o[1] = (bf16)v[1]; o[2] = (bf16)v[2]; o[3] = (bf16)v[3];
        ((bf16x4*)out)[(long)n * V + lane] = o;
    }
}

// ---------------- small-C aggregate (layer 2): thread per channel, strided -------
template <int H, int D, bool ACT, int NPB>
__global__ void gat_aggregate_small(const int* __restrict__ row_ptr, const int* __restrict__ csr_src,
                                    const float* __restrict__ attn, const float* __restrict__ inv_d,
                                    const float* __restrict__ feat, int fstride,
                                    const float* __restrict__ res, int rstride,
                                    const float* __restrict__ bias, float* __restrict__ out, int N) {
    constexpr int C = H * D;
    const int local = threadIdx.x % C;
    const int n = blockIdx.x * NPB + threadIdx.x / C;
    if (n >= N) return;
    const int h = local / D;
    float acc = 0.f;
    const int pend = row_ptr[n + 1];
    for (int p = row_ptr[n]; p < pend; ++p) {
        const int s = csr_src[p];
        acc += attn[p * H + h] * feat[(long)s * fstride + local];
    }
    float v = acc * inv_d[n * H + h] + res[(long)n * rstride + local] + bias[local];
    if (ACT) {
        const float sp = (v > 20.f) ? v : log1pf(expf(v));
        v = v * tanhf(sp);
    }
    out[(long)n * C + local] = v;
}

// ---------------- host orchestration ----------------

static inline int cdiv(long a, long b) { return (int)((a + b - 1) / b); }

extern "C" void kernel_launch(void* const* d_in, const int* in_sizes, int n_in,
                              void* d_out, int out_size, void* d_ws, size_t ws_size,
                              hipStream_t stream) {
    const float* x   = (const float*)d_in[0];
    const int*   src = (const int*)d_in[1];
    const int*   dst = (const int*)d_in[2];
    const float* W0  = (const float*)d_in[3];
    const float* al0 = (const float*)d_in[4];
    const float* ar0 = (const float*)d_in[5];
    const float* b0  = (const float*)d_in[6];
    const float* W1  = (const float*)d_in[7];
    const float* al1 = (const float*)d_in[8];
    const float* ar1 = (const float*)d_in[9];
    const float* b1  = (const float*)d_in[10];
    const float* W2  = (const float*)d_in[11];
    const float* al2 = (const float*)d_in[12];
    const float* ar2 = (const float*)d_in[13];
    const float* b2  = (const float*)d_in[14];
    const float* rW2 = (const float*)d_in[15];
    float* out = (float*)d_out;

    const int N = in_sizes[0] / 256;   // 50000
    const int E = in_sizes[1];         // 800000
    const int K = 256;

    // workspace layout
    bf16* Wt0    = (bf16*)d_ws;               // 256*256 bf16
    bf16* Wt1    = Wt0 + 65536;               // 256*256 bf16
    bf16* Bct    = Wt1 + 65536;               // 32*256 bf16
    bf16* Fb     = Bct + 8192;                // N*256 bf16 feat
    bf16* Hb     = Fb + (long)N * 256;        // N*256 bf16 hidden
    float* F2    = (float*)(Hb + (long)N * 256);  // N*32 (layer2 feat | res)
    float* el    = F2 + (long)N * 32;         // N*4
    float* er    = el + (long)N * 4;          // N*4
    float* inv_d = er + (long)N * 4;          // N*4
    float* attn  = inv_d + (long)N * 4;       // E*4
    unsigned* elmax_u = (unsigned*)(attn + (long)E * 4); // 4
    int* deg     = (int*)(elmax_u + 4);       // N
    int* scanned = deg + N;                   // N
    int* bsums   = scanned + N;               // 64
    int* row_ptr = bsums + 64;                // N+1
    int* cursor  = row_ptr + N + 1;           // N
    int* csr_src = cursor + N;                // E

    const int THREADS = 256;
    const int NB = cdiv(N, 1024);
    dim3 mfma_grid(2, cdiv(N, 128));

    // ---------- weight prep + CSR build (reused by all layers) ----------
    transpose_cast_kernel<<<cdiv(65536, THREADS), THREADS, 0, stream>>>(W0, Wt0, K, 256);
    transpose_cast_kernel<<<cdiv(65536, THREADS), THREADS, 0, stream>>>(W1, Wt1, K, 256);
    concat_w2t_kernel<<<cdiv(32 * 256, THREADS), THREADS, 0, stream>>>(W2, rW2, Bct);
    hipMemsetAsync(deg, 0, (size_t)N * 4, stream);
    count_deg_kernel<<<cdiv(E, THREADS), THREADS, 0, stream>>>(dst, deg, E);
    scan_block_kernel<<<NB, 256, 0, stream>>>(deg, scanned, bsums, N);
    scan_sums_kernel<<<1, 64, 0, stream>>>(bsums, NB);
    apply_offsets_kernel<<<cdiv(N, THREADS), THREADS, 0, stream>>>(scanned, bsums, row_ptr, cursor, N, E);
    scatter_kernel<<<cdiv(E, THREADS), THREADS, 0, stream>>>(src, dst, cursor, csr_src, E);

    // ================= Layer 0 (H=4, D=64), input x (fp32), out Hb (bf16) =========
    gemm_mfma_bf16<float><<<mfma_grid, 256, 0, stream>>>(x, Wt0, Fb, N);
    el_er_node_kernel<<<cdiv(N, 4), 256, 0, stream>>>(Fb, al0, ar0, el, er, N);
    init_elmax_kernel<<<1, 64, 0, stream>>>(elmax_u);
    elmax4_kernel<<<64, 256, 0, stream>>>((const float4*)el, elmax_u, N);
    attn_weight4_onepass<<<cdiv(N, THREADS), THREADS, 0, stream>>>(row_ptr, csr_src, el, er, elmax_u, attn, inv_d, N);
    gat_aggregate_wave<4, 64, true, float, bf16><<<cdiv(N, 4), 256, 0, stream>>>(
        row_ptr, csr_src, attn, inv_d, Fb, x, b0, Hb, N);

    // ================= Layer 1 (H=4, D=64), input Hb (bf16), in-place =============
    gemm_mfma_bf16<bf16><<<mfma_grid, 256, 0, stream>>>(Hb, Wt1, Fb, N);
    el_er_node_kernel<<<cdiv(N, 4), 256, 0, stream>>>(Fb, al1, ar1, el, er, N);
    init_elmax_kernel<<<1, 64, 0, stream>>>(elmax_u);
    elmax4_kernel<<<64, 256, 0, stream>>>((const float4*)el, elmax_u, N);
    attn_weight4_onepass<<<cdiv(N, THREADS), THREADS, 0, stream>>>(row_ptr, csr_src, el, er, elmax_u, attn, inv_d, N);
    gat_aggregate_wave<4, 64, true, bf16, bf16><<<cdiv(N, 4), 256, 0, stream>>>(
        row_ptr, csr_src, attn, inv_d, Fb, Hb, b1, Hb, N);

    // ================= Layer 2 (H=1, D=16): F2 = Hb @ [W2|rW2] =====================
    gemm_mfma_n32<<<cdiv(N, 128), 256, 0, stream>>>(Hb, Bct, F2, N);
    el_er_strided<1, 16><<<cdiv((long)N * 64, THREADS), THREADS, 0, stream>>>(F2, 32, al2, ar2, el, er, N);
    init_elmax_kernel<<<1, 64, 0, stream>>>(elmax_u);
    elmax4_kernel<<<64, 256, 0, stream>>>((const float4*)el, elmax_u, N / 4);
    attn_weight1_onepass<<<cdiv(N, THREADS), THREADS, 0, stream>>>(row_ptr, csr_src, el, er, elmax_u, attn, inv_d, N);
    gat_aggregate_small<1, 16, false, 16><<<cdiv(N, 16), 256, 0, stream>>>(row_ptr, csr_src, attn, inv_d,
                                                                           F2, 32, F2 + 16, 32, b2, out, N);
}